// Round 6
// baseline (8196.144 us; speedup 1.0000x reference)
//
#include <hip/hip_runtime.h>
#include <stdint.h>

#define D 64          // embedding dim
#define SH_I 6        // item rows per dest-bucket = 64   (csr_i: dst=item, src=user)
#define SH_U 7        // user rows per dest-bucket = 128  (csr_u: dst=user, src=item)
#define EPT 4         // edges per thread in passA
#define TILE 2048     // 512 threads * EPT
#define TSH 13        // source tile = 8192 rows = 2MB of embeddings
#define NB_MAX 800    // >= max bucket count (782)

typedef unsigned long long u64;
typedef unsigned int u32;
typedef float f32x4 __attribute__((ext_vector_type(4)));

// ---------------- CSR build ----------------

__global__ __launch_bounds__(1024)
void init_cursors_kernel(int* cur_i, int nb_i, int cap_i,
                         int* cur_u, int nb_u, int cap_u) {
    int t = threadIdx.x;
    for (int q = t; q < nb_i; q += 1024) cur_i[q] = q * cap_i;
    for (int q = t; q < nb_u; q += 1024) cur_u[q] = q * cap_u;
}

// Bin edges by destination bucket for both directions in one pass.
// Record (8B): [val:32][src << SH | dst_in_bucket]
__global__ __launch_bounds__(512)
void passA_kernel(const int* __restrict__ eu, const int* __restrict__ ei,
                  const float* __restrict__ ev, int E,
                  int* __restrict__ cur_i, int nb_i,
                  int* __restrict__ cur_u, int nb_u,
                  u64* __restrict__ stg_i, u64* __restrict__ stg_u) {
    __shared__ int cnt_i[NB_MAX], cnt_u[NB_MAX];
    __shared__ int base_i[NB_MAX], base_u[NB_MAX];
    int tid = threadIdx.x;
    long tile0 = (long)blockIdx.x * TILE;
    for (int q = tid; q < nb_i; q += 512) cnt_i[q] = 0;
    for (int q = tid; q < nb_u; q += 512) cnt_u[q] = 0;
    __syncthreads();
    int uu[EPT], ii[EPT], lo_i[EPT], lo_u[EPT];
    float vv[EPT];
    #pragma unroll
    for (int j = 0; j < EPT; ++j) {
        long e = tile0 + tid + j * 512;
        if (e < E) {
            uu[j] = eu[e]; ii[j] = ei[e]; vv[j] = ev[e];
            lo_i[j] = atomicAdd(&cnt_i[ii[j] >> SH_I], 1);
            lo_u[j] = atomicAdd(&cnt_u[uu[j] >> SH_U], 1);
        } else {
            uu[j] = -1;
        }
    }
    __syncthreads();
    for (int q = tid; q < nb_i; q += 512)
        if (cnt_i[q]) base_i[q] = atomicAdd(&cur_i[q], cnt_i[q]);
    for (int q = tid; q < nb_u; q += 512)
        if (cnt_u[q]) base_u[q] = atomicAdd(&cur_u[q], cnt_u[q]);
    __syncthreads();
    #pragma unroll
    for (int j = 0; j < EPT; ++j) {
        if (uu[j] >= 0) {
            u64 vb = (u64)__float_as_uint(vv[j]) << 32;
            int bi = ii[j] >> SH_I;
            stg_i[base_i[bi] + lo_i[j]] =
                vb | ((u32)uu[j] << SH_I) | (u32)(ii[j] & ((1 << SH_I) - 1));
            int bu = uu[j] >> SH_U;
            stg_u[base_u[bu] + lo_u[j]] =
                vb | ((u32)ii[j] << SH_U) | (u32)(uu[j] & ((1 << SH_U) - 1));
        }
    }
}

// exclusive scan of per-bucket counts -> compact csr bucket bases (nb <= 1024)
__global__ __launch_bounds__(1024)
void bucket_scan_kernel(const int* __restrict__ cur, int nb, int cap,
                        int* __restrict__ bbase) {
    __shared__ int wsum[16];
    int tid = threadIdx.x, lane = tid & 63, wid = tid >> 6;
    int v = (tid < nb) ? (cur[tid] - tid * cap) : 0;
    int x = v;
    #pragma unroll
    for (int d = 1; d < 64; d <<= 1) { int t = __shfl_up(x, d, 64); if (lane >= d) x += t; }
    if (lane == 63) wsum[wid] = x;
    __syncthreads();
    if (tid < 16) {
        int y = wsum[tid];
        #pragma unroll
        for (int d = 1; d < 16; d <<= 1) { int t = __shfl_up(y, d, 16); if (tid >= d) y += t; }
        wsum[tid] = y;
    }
    __syncthreads();
    int excl = ((wid > 0) ? wsum[wid - 1] : 0) + x - v;
    if (tid < nb) bbase[tid] = excl;
}

// Per bucket: sort edges by source tile (stable-ish, order within tile free).
// Records pass through unchanged; only the order changes.
__global__ __launch_bounds__(512)
void passB_kernel(int nb_i, int cap_i, int T_u_, int nb_u, int cap_u, int T_i_,
                  const int* __restrict__ cur_i, const int* __restrict__ cur_u,
                  const int* __restrict__ bb_i, const int* __restrict__ bb_u,
                  const u64* __restrict__ stg_i, const u64* __restrict__ stg_u,
                  u64* __restrict__ csr_i, u64* __restrict__ csr_u) {
    __shared__ int lcnt[16];
    __shared__ int lofs[16];
    int b = blockIdx.x;
    bool item_dir = (b < nb_i);
    int bb2 = item_dir ? b : b - nb_i;
    int SH = item_dir ? SH_I : SH_U;
    int T  = item_dir ? T_u_ : T_i_;       // tiles over SOURCE rows
    int cap = item_dir ? cap_i : cap_u;
    const u64* stg = item_dir ? stg_i : stg_u;
    u64* csr = item_dir ? csr_i : csr_u;
    int ebase = item_dir ? bb_i[bb2] : bb_u[bb2];
    int cnt = (item_dir ? cur_i[bb2] : cur_u[bb2]) - bb2 * cap;
    int sbeg = bb2 * cap;
    int tid = threadIdx.x;
    if (tid < 16) lcnt[tid] = 0;
    __syncthreads();
    for (int k = tid; k < cnt; k += 512) {
        int tile = (int)(((u32)stg[sbeg + k]) >> SH) >> TSH;
        atomicAdd(&lcnt[tile], 1);
    }
    __syncthreads();
    if (tid == 0) {
        int run = 0;
        for (int t = 0; t < T; ++t) { lofs[t] = run; run += lcnt[t]; }
    }
    __syncthreads();
    for (int k = tid; k < cnt; k += 512) {
        u64 rec = stg[sbeg + k];
        int tile = (int)(((u32)rec) >> SH) >> TSH;
        int pos = ebase + atomicAdd(&lofs[tile], 1);
        csr[pos] = rec;
    }
}

// ---------------- propagation ----------------

// Edge-parallel SpMM with LDS destination accumulators.
// Block owns 2^SH dest rows (acc in LDS). Edges are tile-sorted; wave w takes
// 8-edge chunks strided by 64 so all waves stay within ~64 edges of each other
// (keeps the current source tile L2-hot). Per edge: wave-uniform record load,
// coalesced 256B row gather (lane = dim), ds_add_f32 into the LDS row.
template<int SH>
__global__ __launch_bounds__(512)
void spmm3_kernel(const u64* __restrict__ csr, const int* __restrict__ bb,
                  const int* __restrict__ cur, int cap,
                  const float* __restrict__ src_emb,
                  float* __restrict__ dst_emb,
                  const float* __restrict__ sum_in, float* __restrict__ sum_out,
                  int N, int write_dst) {
    constexpr int ROWS = 1 << SH;
    __shared__ __align__(16) float acc[ROWS * D];
    int b = blockIdx.x;
    int tid = threadIdx.x;
    #pragma unroll
    for (int q = tid; q < ROWS * 16; q += 512)
        ((f32x4*)acc)[q] = (f32x4){0.f, 0.f, 0.f, 0.f};
    __syncthreads();
    int ebase = bb[b];
    int cnt = cur[b] - b * cap;
    int w = tid >> 6, lane = tid & 63;
    const int U = 8;
    for (int rk = w * U; rk < cnt; rk += 8 * U) {
        int m = cnt - rk;
        u64 r[U];
        #pragma unroll
        for (int t = 0; t < U; ++t)
            r[t] = (t < m) ? __builtin_nontemporal_load(csr + ebase + rk + t) : 0ull;
        #pragma unroll
        for (int t = 0; t < U; ++t) {
            if (t < m) {
                u32 lo = (u32)r[t];
                float v = __uint_as_float((u32)(r[t] >> 32));
                int src = (int)(lo >> SH);
                int dst = (int)(lo & (ROWS - 1));
                float x = src_emb[(size_t)src * D + lane];
                (void)__hip_atomic_fetch_add(&acc[dst * D + lane], v * x,
                                             __ATOMIC_RELAXED,
                                             __HIP_MEMORY_SCOPE_WORKGROUP);
            }
        }
    }
    __syncthreads();
    int rows0 = b << SH;
    int nr = min(ROWS, N - rows0);
    for (int q = tid; q < nr * 16; q += 512) {
        f32x4 a = ((const f32x4*)acc)[q];
        size_t go = (size_t)rows0 * 16 + q;
        if (write_dst) __builtin_nontemporal_store(a, (f32x4*)dst_emb + go);
        f32x4 s = ((const f32x4*)sum_in)[go];
        __builtin_nontemporal_store(s + a, (f32x4*)sum_out + go);
    }
}

__global__ __launch_bounds__(256)
void score_kernel(const float* __restrict__ sum_u, const float* __restrict__ sum_i,
                  const int* __restrict__ users, const int* __restrict__ items,
                  float* __restrict__ out, int B, float inv2) {
    int gid = blockIdx.x * blockDim.x + threadIdx.x;
    int b = gid >> 4;
    int lane = gid & 15;
    if (b >= B) return;
    int u = users[b], it = items[b];
    float4 a = ((const float4*)(sum_u + (size_t)u * D))[lane];
    float4 c = ((const float4*)(sum_i + (size_t)it * D))[lane];
    float d = a.x * c.x + a.y * c.y + a.z * c.z + a.w * c.w;
    #pragma unroll
    for (int m = 1; m < 16; m <<= 1) d += __shfl_xor(d, m, 64);
    if (lane == 0) out[b] = d * inv2;
}

// ---------------- launch ----------------

extern "C" void kernel_launch(void* const* d_in, const int* in_sizes, int n_in,
                              void* d_out, int out_size, void* d_ws, size_t ws_size,
                              hipStream_t stream) {
    const float* user_emb = (const float*)d_in[0];
    const float* item_emb = (const float*)d_in[1];
    const float* edge_vals = (const float*)d_in[2];
    const int* edge_u = (const int*)d_in[3];
    const int* edge_i = (const int*)d_in[4];
    const int* users = (const int*)d_in[5];
    const int* items = (const int*)d_in[6];
    float* out = (float*)d_out;

    const int U = in_sizes[0] / D;
    const int I = in_sizes[1] / D;
    const int E = in_sizes[2];
    const int B = in_sizes[5];

    const int nb_i = (I + (1 << SH_I) - 1) >> SH_I;   // 782 item dest-buckets
    const int nb_u = (U + (1 << SH_U) - 1) >> SH_U;   // 782 user dest-buckets
    const int T_u = (U + (1 << TSH) - 1) >> TSH;      // source tiles over users (13)
    const int T_i = (I + (1 << TSH) - 1) >> TSH;      // source tiles over items (7)
    const int cap_i = ((E / nb_i + E / (8 * nb_i) + 256 + 63) / 64) * 64;
    const int cap_u = ((E / nb_u + E / (8 * nb_u) + 256 + 63) / 64) * 64;

    // carve workspace (256B aligned)
    char* p = (char*)d_ws;
    size_t off = 0;
    auto alloc = [&](size_t bytes) -> char* {
        char* r = p + off;
        off = (off + bytes + 255) & ~(size_t)255;
        return r;
    };
    float* sum_u  = (float*)alloc((size_t)U * D * 4);
    float* sum_i  = (float*)alloc((size_t)I * D * 4);
    float* euA    = (float*)alloc((size_t)U * D * 4);
    float* eiA    = (float*)alloc((size_t)I * D * 4);
    u64* csr_u    = (u64*)alloc((size_t)(E + 16) * 8);
    u64* csr_i    = (u64*)alloc((size_t)(E + 16) * 8);
    int* cur_i    = (int*)alloc((size_t)nb_i * 4);
    int* cur_u    = (int*)alloc((size_t)nb_u * 4);
    int* bb_i     = (int*)alloc((size_t)nb_i * 4);
    int* bb_u     = (int*)alloc((size_t)nb_u * 4);
    u64* stg_i    = (u64*)alloc((size_t)nb_i * cap_i * 8);
    u64* stg_u    = (u64*)alloc((size_t)nb_u * cap_u * 8);
    // stg_* are dead after passB: alias the layer ping-pong buffers over them
    float* euB = (float*)stg_i;   // U*D*4 = 25.6MB <= nb_i*cap_i*8 (~29MB)
    float* eiB = (float*)stg_u;   // I*D*4 = 12.8MB
    if (off > ws_size) return;    // workspace too small -> fail loudly

    // 1. CSR build: bucket by dest, then tile-sort by source
    init_cursors_kernel<<<1, 1024, 0, stream>>>(cur_i, nb_i, cap_i, cur_u, nb_u, cap_u);
    int tiles = (int)((E + TILE - 1) / TILE);
    passA_kernel<<<tiles, 512, 0, stream>>>(edge_u, edge_i, edge_vals, E,
                                            cur_i, nb_i, cur_u, nb_u, stg_i, stg_u);
    bucket_scan_kernel<<<1, 1024, 0, stream>>>(cur_i, nb_i, cap_i, bb_i);
    bucket_scan_kernel<<<1, 1024, 0, stream>>>(cur_u, nb_u, cap_u, bb_u);
    passB_kernel<<<nb_i + nb_u, 512, 0, stream>>>(nb_i, cap_i, T_u,
                                                  nb_u, cap_u, T_i,
                                                  cur_i, cur_u, bb_i, bb_u,
                                                  stg_i, stg_u, csr_i, csr_u);

    // 2. three propagation layers (Jacobi: both SpMMs read the old layer)
    // layer 0 (sum_in = original embeddings -> fuses the sum init)
    spmm3_kernel<SH_I><<<nb_i, 512, 0, stream>>>(csr_i, bb_i, cur_i, cap_i,
                                                 user_emb, eiA, item_emb, sum_i, I, 1);
    spmm3_kernel<SH_U><<<nb_u, 512, 0, stream>>>(csr_u, bb_u, cur_u, cap_u,
                                                 item_emb, euA, user_emb, sum_u, U, 1);
    // layer 1
    spmm3_kernel<SH_I><<<nb_i, 512, 0, stream>>>(csr_i, bb_i, cur_i, cap_i,
                                                 euA, eiB, sum_i, sum_i, I, 1);
    spmm3_kernel<SH_U><<<nb_u, 512, 0, stream>>>(csr_u, bb_u, cur_u, cap_u,
                                                 eiA, euB, sum_u, sum_u, U, 1);
    // layer 2 (dst never read again -> skip dst write)
    spmm3_kernel<SH_I><<<nb_i, 512, 0, stream>>>(csr_i, bb_i, cur_i, cap_i,
                                                 euB, eiA, sum_i, sum_i, I, 0);
    spmm3_kernel<SH_U><<<nb_u, 512, 0, stream>>>(csr_u, bb_u, cur_u, cap_u,
                                                 eiB, euA, sum_u, sum_u, U, 0);

    // 3. final scores: inv^2 * dot(sum_u[u], sum_i[i]), inv = 1/(L+1) = 1/4
    int blk_s = (B * 16 + 255) / 256;
    score_kernel<<<blk_s, 256, 0, stream>>>(sum_u, sum_i, users, items, out, B, 0.0625f);
}

// Round 7
// 519.827 us; speedup vs baseline: 15.7671x; 15.7671x over previous
//
#include <hip/hip_runtime.h>
#include <stdint.h>

#define D 64          // embedding dim
#define SH_I 8        // item rows per bucket = 256
#define SH_U 9        // user rows per bucket = 512
#define EPT 4         // edges per thread in passA
#define TILE 2048     // 512 threads * EPT

typedef unsigned long long u64;
typedef unsigned int u32;

// ---------------- bf16 helpers ----------------

__device__ __forceinline__ u32 bf16_rne(float f) {
    u32 x = __float_as_uint(f);
    return (x + 0x7fffu + ((x >> 16) & 1u)) >> 16;
}
__device__ __forceinline__ u32 pack2_bf16(float a, float b) {
    return bf16_rne(a) | (bf16_rne(b) << 16);
}

// f32 pairs -> packed bf16 (u32 holds 2 elems)
__global__ __launch_bounds__(256)
void cvt_bf16_kernel(const float2* __restrict__ src, u32* __restrict__ dst, long n2) {
    long i = (long)blockIdx.x * blockDim.x + threadIdx.x;
    long stride = (long)gridDim.x * blockDim.x;
    for (; i < n2; i += stride) {
        float2 f = src[i];
        dst[i] = pack2_bf16(f.x, f.y);
    }
}

// ---------------- CSR build ----------------

__global__ __launch_bounds__(512)
void init_cursors_kernel(int* cur_i, int nb_i, int cap_i,
                         int* cur_u, int nb_u, int cap_u) {
    int t = threadIdx.x;
    if (t < nb_i) cur_i[t] = t * cap_i;
    if (t < nb_u) cur_u[t] = t * cap_u;
}

// Bin edges by destination bucket for both directions in one pass.
// Record (8B): [val:32][src << SH | dst_in_bucket]
__global__ __launch_bounds__(512)
void passA_kernel(const int* __restrict__ eu, const int* __restrict__ ei,
                  const float* __restrict__ ev, int E,
                  int* __restrict__ cur_i, int nb_i,
                  int* __restrict__ cur_u, int nb_u,
                  u64* __restrict__ stg_i, u64* __restrict__ stg_u) {
    __shared__ int cnt_i[256], cnt_u[256];
    __shared__ int base_i[256], base_u[256];
    int tid = threadIdx.x;
    long tile0 = (long)blockIdx.x * TILE;
    if (tid < 256) { cnt_i[tid] = 0; cnt_u[tid] = 0; }
    __syncthreads();
    int uu[EPT], ii[EPT], lo_i[EPT], lo_u[EPT];
    float vv[EPT];
    #pragma unroll
    for (int j = 0; j < EPT; ++j) {
        long e = tile0 + tid + j * 512;
        if (e < E) {
            uu[j] = eu[e]; ii[j] = ei[e]; vv[j] = ev[e];
            lo_i[j] = atomicAdd(&cnt_i[ii[j] >> SH_I], 1);
            lo_u[j] = atomicAdd(&cnt_u[uu[j] >> SH_U], 1);
        } else {
            uu[j] = -1;
        }
    }
    __syncthreads();
    if (tid < nb_i && cnt_i[tid]) base_i[tid] = atomicAdd(&cur_i[tid], cnt_i[tid]);
    if (tid < nb_u && cnt_u[tid]) base_u[tid] = atomicAdd(&cur_u[tid], cnt_u[tid]);
    __syncthreads();
    #pragma unroll
    for (int j = 0; j < EPT; ++j) {
        if (uu[j] >= 0) {
            u64 vb = (u64)__float_as_uint(vv[j]) << 32;
            int bi = ii[j] >> SH_I;
            stg_i[base_i[bi] + lo_i[j]] =
                vb | ((u32)uu[j] << SH_I) | (u32)(ii[j] & ((1 << SH_I) - 1));
            int bu = uu[j] >> SH_U;
            stg_u[base_u[bu] + lo_u[j]] =
                vb | ((u32)ii[j] << SH_U) | (u32)(uu[j] & ((1 << SH_U) - 1));
        }
    }
}

// exclusive scan of per-bucket counts -> bucket edge bases; write rowp sentinel
__global__ __launch_bounds__(512)
void bucket_scan_kernel(const int* __restrict__ cur, int nb, int cap, int E,
                        int* __restrict__ bbase, int* __restrict__ rowp_sentinel) {
    __shared__ int wsum[8];
    int tid = threadIdx.x, lane = tid & 63, wid = tid >> 6;
    int v = (tid < nb) ? (cur[tid] - tid * cap) : 0;
    int x = v;
    #pragma unroll
    for (int d = 1; d < 64; d <<= 1) { int t = __shfl_up(x, d, 64); if (lane >= d) x += t; }
    if (lane == 63) wsum[wid] = x;
    __syncthreads();
    if (tid < 8) {
        int y = wsum[tid];
        #pragma unroll
        for (int d = 1; d < 8; d <<= 1) { int t = __shfl_up(y, d, 8); if (tid >= d) y += t; }
        wsum[tid] = y;
    }
    __syncthreads();
    int excl = ((wid > 0) ? wsum[wid - 1] : 0) + x - v;
    if (tid < nb) bbase[tid] = excl;
    if (tid == 0) *rowp_sentinel = E;
}

// Per bucket: LDS row-histogram + block scan -> rowptr; then place into final CSR.
__global__ __launch_bounds__(512)
void passB_kernel(int nb_i, int cap_i, int N_i,
                  int nb_u, int cap_u, int N_u,
                  const int* __restrict__ cur_i, const int* __restrict__ cur_u,
                  const int* __restrict__ bb_i, const int* __restrict__ bb_u,
                  const u64* __restrict__ stg_i, const u64* __restrict__ stg_u,
                  int* __restrict__ rowp_i, int* __restrict__ rowp_u,
                  int2* __restrict__ csr_i, int2* __restrict__ csr_u) {
    __shared__ int lcnt[512];
    __shared__ int wsum[8];
    int b = blockIdx.x;
    int dir_item = (b < nb_i);
    int bb = dir_item ? b : b - nb_i;
    int SH = dir_item ? SH_I : SH_U;
    int cap = dir_item ? cap_i : cap_u;
    int N = dir_item ? N_i : N_u;
    const u64* stg = dir_item ? stg_i : stg_u;
    int ebase = dir_item ? bb_i[bb] : bb_u[bb];
    int scount = (dir_item ? cur_i[bb] : cur_u[bb]) - bb * cap;
    int* rowp = dir_item ? rowp_i : rowp_u;
    int2* csr = dir_item ? csr_i : csr_u;

    int rows0 = bb << SH;
    int nrows = min(1 << SH, N - rows0);
    int sbeg = bb * cap;
    int tid = threadIdx.x;
    int mask = (1 << SH) - 1;

    lcnt[tid] = 0;
    __syncthreads();
    for (int k = tid; k < scount; k += 512) {
        int rin = (int)((u32)stg[sbeg + k] & mask);
        atomicAdd(&lcnt[rin], 1);
    }
    __syncthreads();
    // exclusive scan over lcnt[0..511]
    int lane = tid & 63, wid = tid >> 6;
    int v = lcnt[tid];
    int x = v;
    #pragma unroll
    for (int d = 1; d < 64; d <<= 1) { int t = __shfl_up(x, d, 64); if (lane >= d) x += t; }
    if (lane == 63) wsum[wid] = x;
    __syncthreads();
    if (tid < 8) {
        int y = wsum[tid];
        #pragma unroll
        for (int d = 1; d < 8; d <<= 1) { int t = __shfl_up(y, d, 8); if (tid >= d) y += t; }
        wsum[tid] = y;
    }
    __syncthreads();
    int excl = ((wid > 0) ? wsum[wid - 1] : 0) + x - v;
    lcnt[tid] = excl;                       // becomes bucket-local running cursor
    if (tid < nrows) rowp[rows0 + tid] = ebase + excl;
    __syncthreads();
    for (int k = tid; k < scount; k += 512) {
        u64 rec = stg[sbeg + k];
        int rin = (int)((u32)rec & mask);
        int src = (int)(((u32)rec) >> SH);
        int pos = ebase + atomicAdd(&lcnt[rin], 1);
        csr[pos] = make_int2(src, (int)(rec >> 32));
    }
}

// ---------------- propagation ----------------

// Wave-per-row SpMM over a packed-bf16 source table, 16 edges in flight.
// lane = (g:2 | el:4): subgroup g handles edges k+g, k+g+4, k+g+8, k+g+12;
// el indexes the row's uint2 (4 bf16 = dims el*4..el*4+3). Masked tail.
// Accumulation f32. Outputs: dst16 (packed bf16, for next layer's gather)
// and sum_out = sum_in + acc (f32).
__global__ __launch_bounds__(256)
void spmm_kernel(const int* __restrict__ rowptr, const int2* __restrict__ csr,
                 const u32* __restrict__ src16, u32* __restrict__ dst16,
                 const float* __restrict__ sum_in, float* __restrict__ sum_out,
                 int nrows, int write_dst) {
    int row = blockIdx.x * 4 + (threadIdx.x >> 6);
    if (row >= nrows) return;
    int lane = threadIdx.x & 63;
    int g = lane >> 4;
    int el = lane & 15;
    int beg = rowptr[row], end = rowptr[row + 1];
    const uint2* SB = (const uint2*)src16 + el;   // row stride = 16 uint2 (128B)
    float4 A0 = {0,0,0,0}, A1 = {0,0,0,0}, A2 = {0,0,0,0}, A3 = {0,0,0,0};
    for (int k = beg + g; k < end; k += 16) {
        int2 r0 = csr[k];
        int2 r1 = csr[k + 4];
        int2 r2 = csr[k + 8];
        int2 r3 = csr[k + 12];
        bool m1 = (k + 4) < end, m2 = (k + 8) < end, m3 = (k + 12) < end;
        int s0 = r0.x;
        int s1 = m1 ? r1.x : 0;
        int s2 = m2 ? r2.x : 0;
        int s3 = m3 ? r3.x : 0;
        float v0 = __int_as_float(r0.y);
        float v1 = m1 ? __int_as_float(r1.y) : 0.f;
        float v2 = m2 ? __int_as_float(r2.y) : 0.f;
        float v3 = m3 ? __int_as_float(r3.y) : 0.f;
        uint2 w0 = SB[(size_t)s0 * 16];
        uint2 w1 = SB[(size_t)s1 * 16];
        uint2 w2 = SB[(size_t)s2 * 16];
        uint2 w3 = SB[(size_t)s3 * 16];
        A0.x += v0 * __uint_as_float(w0.x << 16);
        A0.y += v0 * __uint_as_float(w0.x & 0xffff0000u);
        A0.z += v0 * __uint_as_float(w0.y << 16);
        A0.w += v0 * __uint_as_float(w0.y & 0xffff0000u);
        A1.x += v1 * __uint_as_float(w1.x << 16);
        A1.y += v1 * __uint_as_float(w1.x & 0xffff0000u);
        A1.z += v1 * __uint_as_float(w1.y << 16);
        A1.w += v1 * __uint_as_float(w1.y & 0xffff0000u);
        A2.x += v2 * __uint_as_float(w2.x << 16);
        A2.y += v2 * __uint_as_float(w2.x & 0xffff0000u);
        A2.z += v2 * __uint_as_float(w2.y << 16);
        A2.w += v2 * __uint_as_float(w2.y & 0xffff0000u);
        A3.x += v3 * __uint_as_float(w3.x << 16);
        A3.y += v3 * __uint_as_float(w3.x & 0xffff0000u);
        A3.z += v3 * __uint_as_float(w3.y << 16);
        A3.w += v3 * __uint_as_float(w3.y & 0xffff0000u);
    }
    float4 a;
    a.x = (A0.x + A1.x) + (A2.x + A3.x);
    a.y = (A0.y + A1.y) + (A2.y + A3.y);
    a.z = (A0.z + A1.z) + (A2.z + A3.z);
    a.w = (A0.w + A1.w) + (A2.w + A3.w);
    a.x += __shfl_xor(a.x, 16, 64); a.x += __shfl_xor(a.x, 32, 64);
    a.y += __shfl_xor(a.y, 16, 64); a.y += __shfl_xor(a.y, 32, 64);
    a.z += __shfl_xor(a.z, 16, 64); a.z += __shfl_xor(a.z, 32, 64);
    a.w += __shfl_xor(a.w, 16, 64); a.w += __shfl_xor(a.w, 32, 64);
    if (g == 0) {
        if (write_dst)
            ((uint2*)dst16)[(size_t)row * 16 + el] =
                make_uint2(pack2_bf16(a.x, a.y), pack2_bf16(a.z, a.w));
        float4 s = ((const float4*)(sum_in + (size_t)row * D))[el];
        s.x += a.x; s.y += a.y; s.z += a.z; s.w += a.w;
        ((float4*)(sum_out + (size_t)row * D))[el] = s;
    }
}

__global__ __launch_bounds__(256)
void score_kernel(const float* __restrict__ sum_u, const float* __restrict__ sum_i,
                  const int* __restrict__ users, const int* __restrict__ items,
                  float* __restrict__ out, int B, float inv2) {
    int gid = blockIdx.x * blockDim.x + threadIdx.x;
    int b = gid >> 4;
    int lane = gid & 15;
    if (b >= B) return;
    int u = users[b], it = items[b];
    float4 a = ((const float4*)(sum_u + (size_t)u * D))[lane];
    float4 c = ((const float4*)(sum_i + (size_t)it * D))[lane];
    float d = a.x * c.x + a.y * c.y + a.z * c.z + a.w * c.w;
    #pragma unroll
    for (int m = 1; m < 16; m <<= 1) d += __shfl_xor(d, m, 64);
    if (lane == 0) out[b] = d * inv2;
}

// ---------------- launch ----------------

extern "C" void kernel_launch(void* const* d_in, const int* in_sizes, int n_in,
                              void* d_out, int out_size, void* d_ws, size_t ws_size,
                              hipStream_t stream) {
    const float* user_emb = (const float*)d_in[0];
    const float* item_emb = (const float*)d_in[1];
    const float* edge_vals = (const float*)d_in[2];
    const int* edge_u = (const int*)d_in[3];
    const int* edge_i = (const int*)d_in[4];
    const int* users = (const int*)d_in[5];
    const int* items = (const int*)d_in[6];
    float* out = (float*)d_out;

    const int U = in_sizes[0] / D;
    const int I = in_sizes[1] / D;
    const int E = in_sizes[2];
    const int B = in_sizes[5];

    const int nb_i = (I + (1 << SH_I) - 1) >> SH_I;
    const int nb_u = (U + (1 << SH_U) - 1) >> SH_U;
    const int cap_i = ((E / nb_i + E / (16 * nb_i) + 512 + 63) / 64) * 64;
    const int cap_u = ((E / nb_u + E / (16 * nb_u) + 512 + 63) / 64) * 64;

    // carve workspace (256B aligned)
    char* p = (char*)d_ws;
    size_t off = 0;
    auto alloc = [&](size_t bytes) -> char* {
        char* r = p + off;
        off = (off + bytes + 255) & ~(size_t)255;
        return r;
    };
    float* sum_u  = (float*)alloc((size_t)U * D * 4);
    float* sum_i  = (float*)alloc((size_t)I * D * 4);
    u32* ub16     = (u32*)alloc((size_t)U * (D / 2) * 4);   // packed bf16 originals
    u32* ib16     = (u32*)alloc((size_t)I * (D / 2) * 4);
    int2* csr_u   = (int2*)alloc((size_t)(E + 16) * 8);
    int2* csr_i   = (int2*)alloc((size_t)(E + 16) * 8);
    int* rowp_u   = (int*)alloc((size_t)(U + 1) * 4);
    int* rowp_i   = (int*)alloc((size_t)(I + 1) * 4);
    int* cur_i    = (int*)alloc((size_t)nb_i * 4);
    int* cur_u    = (int*)alloc((size_t)nb_u * 4);
    int* bb_i     = (int*)alloc((size_t)nb_i * 4);
    int* bb_u     = (int*)alloc((size_t)nb_u * 4);
    u64* stg_i    = (u64*)alloc((size_t)nb_i * cap_i * 8);
    u64* stg_u    = (u64*)alloc((size_t)nb_u * cap_u * 8);
    // stg_* dead after passB: alias the bf16 layer ping-pong buffers over them
    // (euX16 = U*32*4 = 12.8MB, eiX16 = I*32*4 = 6.4MB; each stg is ~28MB)
    u32* euA16 = (u32*)stg_i;
    u32* eiA16 = (u32*)((char*)stg_i + (((size_t)U * (D / 2) * 4 + 255) & ~(size_t)255));
    u32* euB16 = (u32*)stg_u;
    u32* eiB16 = (u32*)((char*)stg_u + (((size_t)U * (D / 2) * 4 + 255) & ~(size_t)255));
    if (off > ws_size) return;    // workspace too small -> fail loudly

    // 0. convert original embeddings to packed bf16 gather tables
    cvt_bf16_kernel<<<1024, 256, 0, stream>>>((const float2*)user_emb, ub16, (long)U * (D / 2));
    cvt_bf16_kernel<<<1024, 256, 0, stream>>>((const float2*)item_emb, ib16, (long)I * (D / 2));

    // 1. CSR build (both directions)
    init_cursors_kernel<<<1, 512, 0, stream>>>(cur_i, nb_i, cap_i, cur_u, nb_u, cap_u);
    int tiles = (int)((E + TILE - 1) / TILE);
    passA_kernel<<<tiles, 512, 0, stream>>>(edge_u, edge_i, edge_vals, E,
                                            cur_i, nb_i, cur_u, nb_u, stg_i, stg_u);
    bucket_scan_kernel<<<1, 512, 0, stream>>>(cur_i, nb_i, cap_i, E, bb_i, rowp_i + I);
    bucket_scan_kernel<<<1, 512, 0, stream>>>(cur_u, nb_u, cap_u, E, bb_u, rowp_u + U);
    passB_kernel<<<nb_i + nb_u, 512, 0, stream>>>(nb_i, cap_i, I, nb_u, cap_u, U,
                                                  cur_i, cur_u, bb_i, bb_u,
                                                  stg_i, stg_u, rowp_i, rowp_u,
                                                  csr_i, csr_u);

    // 2. three propagation layers (Jacobi: both SpMMs read the old layer's bf16)
    int blk_i = (I + 3) / 4;
    int blk_u = (U + 3) / 4;
    // layer 0 (sum_in = original f32 embeddings -> fuses sum init)
    spmm_kernel<<<blk_i, 256, 0, stream>>>(rowp_i, csr_i, ub16, eiA16, item_emb, sum_i, I, 1);
    spmm_kernel<<<blk_u, 256, 0, stream>>>(rowp_u, csr_u, ib16, euA16, user_emb, sum_u, U, 1);
    // layer 1
    spmm_kernel<<<blk_i, 256, 0, stream>>>(rowp_i, csr_i, euA16, eiB16, sum_i, sum_i, I, 1);
    spmm_kernel<<<blk_u, 256, 0, stream>>>(rowp_u, csr_u, eiA16, euB16, sum_u, sum_u, U, 1);
    // layer 2 (dst never gathered again -> skip dst write)
    spmm_kernel<<<blk_i, 256, 0, stream>>>(rowp_i, csr_i, euB16, eiA16, sum_i, sum_i, I, 0);
    spmm_kernel<<<blk_u, 256, 0, stream>>>(rowp_u, csr_u, eiB16, euA16, sum_u, sum_u, U, 0);

    // 3. final scores: inv^2 * dot(sum_u[u], sum_i[i]), inv = 1/(L+1) = 1/4
    int blk_s = (B * 16 + 255) / 256;
    score_kernel<<<blk_s, 256, 0, stream>>>(sum_u, sum_i, users, items, out, B, 0.0625f);
}

// Round 8
// 414.439 us; speedup vs baseline: 19.7765x; 1.2543x over previous
//
#include <hip/hip_runtime.h>
#include <stdint.h>

#define D 64          // embedding dim
#define SH_I 8        // item rows per bucket = 256
#define SH_U 9        // user rows per bucket = 512
#define EPT 8         // edges per thread in passA
#define TILE 4096     // 512 threads * EPT

typedef unsigned long long u64;
typedef unsigned int u32;

// ---------------- bf16 helpers ----------------

__device__ __forceinline__ u32 bf16_rne(float f) {
    u32 x = __float_as_uint(f);
    return (x + 0x7fffu + ((x >> 16) & 1u)) >> 16;
}
__device__ __forceinline__ u32 pack2_bf16(float a, float b) {
    return bf16_rne(a) | (bf16_rne(b) << 16);
}

// f32 pairs -> packed bf16 (u32 holds 2 elems)
__global__ __launch_bounds__(256)
void cvt_bf16_kernel(const float2* __restrict__ src, u32* __restrict__ dst, long n2) {
    long i = (long)blockIdx.x * blockDim.x + threadIdx.x;
    long stride = (long)gridDim.x * blockDim.x;
    for (; i < n2; i += stride) {
        float2 f = src[i];
        dst[i] = pack2_bf16(f.x, f.y);
    }
}

// ---------------- CSR build ----------------
// Edge record (4B): [val_bf16_sans_sign:15 | src:17]   (val > 0 always)
// Staging record (8B): [dst_in_bucket:32][rec:32]

__global__ __launch_bounds__(512)
void init_cursors_kernel(int* cur_i, int nb_i, int cap_i,
                         int* cur_u, int nb_u, int cap_u) {
    int t = threadIdx.x;
    if (t < nb_i) cur_i[t] = t * cap_i;
    if (t < nb_u) cur_u[t] = t * cap_u;
}

__global__ __launch_bounds__(512)
void passA_kernel(const int* __restrict__ eu, const int* __restrict__ ei,
                  const float* __restrict__ ev, int E,
                  int* __restrict__ cur_i, int nb_i,
                  int* __restrict__ cur_u, int nb_u,
                  u64* __restrict__ stg_i, u64* __restrict__ stg_u) {
    __shared__ int cnt_i[256], cnt_u[256];
    __shared__ int base_i[256], base_u[256];
    int tid = threadIdx.x;
    long tile0 = (long)blockIdx.x * TILE;
    if (tid < 256) { cnt_i[tid] = 0; cnt_u[tid] = 0; }
    __syncthreads();
    int uu[EPT], ii[EPT], lo_i[EPT], lo_u[EPT];
    u32 vv[EPT];
    #pragma unroll
    for (int j = 0; j < EPT; ++j) {
        long e = tile0 + tid + j * 512;
        if (e < E) {
            uu[j] = eu[e]; ii[j] = ei[e];
            vv[j] = bf16_rne(ev[e]) & 0x7fffu;
            lo_i[j] = atomicAdd(&cnt_i[ii[j] >> SH_I], 1);
            lo_u[j] = atomicAdd(&cnt_u[uu[j] >> SH_U], 1);
        } else {
            uu[j] = -1;
        }
    }
    __syncthreads();
    if (tid < nb_i && cnt_i[tid]) base_i[tid] = atomicAdd(&cur_i[tid], cnt_i[tid]);
    if (tid < nb_u && cnt_u[tid]) base_u[tid] = atomicAdd(&cur_u[tid], cnt_u[tid]);
    __syncthreads();
    #pragma unroll
    for (int j = 0; j < EPT; ++j) {
        if (uu[j] >= 0) {
            int bi = ii[j] >> SH_I;
            u32 rec_i = (vv[j] << 17) | (u32)uu[j];
            stg_i[base_i[bi] + lo_i[j]] =
                ((u64)(u32)(ii[j] & ((1 << SH_I) - 1)) << 32) | rec_i;
            int bu = uu[j] >> SH_U;
            u32 rec_u = (vv[j] << 17) | (u32)ii[j];
            stg_u[base_u[bu] + lo_u[j]] =
                ((u64)(u32)(uu[j] & ((1 << SH_U) - 1)) << 32) | rec_u;
        }
    }
}

// exclusive scan of per-bucket counts -> bucket edge bases; write rowp sentinel
__global__ __launch_bounds__(512)
void bucket_scan_kernel(const int* __restrict__ cur, int nb, int cap, int E,
                        int* __restrict__ bbase, int* __restrict__ rowp_sentinel) {
    __shared__ int wsum[8];
    int tid = threadIdx.x, lane = tid & 63, wid = tid >> 6;
    int v = (tid < nb) ? (cur[tid] - tid * cap) : 0;
    int x = v;
    #pragma unroll
    for (int d = 1; d < 64; d <<= 1) { int t = __shfl_up(x, d, 64); if (lane >= d) x += t; }
    if (lane == 63) wsum[wid] = x;
    __syncthreads();
    if (tid < 8) {
        int y = wsum[tid];
        #pragma unroll
        for (int d = 1; d < 8; d <<= 1) { int t = __shfl_up(y, d, 8); if (tid >= d) y += t; }
        wsum[tid] = y;
    }
    __syncthreads();
    int excl = ((wid > 0) ? wsum[wid - 1] : 0) + x - v;
    if (tid < nb) bbase[tid] = excl;
    if (tid == 0) *rowp_sentinel = E;
}

// Per bucket: LDS row-histogram + block scan -> rowptr; place 4B recs into CSR.
__global__ __launch_bounds__(512)
void passB_kernel(int nb_i, int cap_i, int N_i,
                  int nb_u, int cap_u, int N_u,
                  const int* __restrict__ cur_i, const int* __restrict__ cur_u,
                  const int* __restrict__ bb_i, const int* __restrict__ bb_u,
                  const u64* __restrict__ stg_i, const u64* __restrict__ stg_u,
                  int* __restrict__ rowp_i, int* __restrict__ rowp_u,
                  u32* __restrict__ csr_i, u32* __restrict__ csr_u) {
    __shared__ int lcnt[512];
    __shared__ int wsum[8];
    int b = blockIdx.x;
    int dir_item = (b < nb_i);
    int bb = dir_item ? b : b - nb_i;
    int SH = dir_item ? SH_I : SH_U;
    int cap = dir_item ? cap_i : cap_u;
    int N = dir_item ? N_i : N_u;
    const u64* stg = dir_item ? stg_i : stg_u;
    int ebase = dir_item ? bb_i[bb] : bb_u[bb];
    int scount = (dir_item ? cur_i[bb] : cur_u[bb]) - bb * cap;
    int* rowp = dir_item ? rowp_i : rowp_u;
    u32* csr = dir_item ? csr_i : csr_u;

    int rows0 = bb << SH;
    int nrows = min(1 << SH, N - rows0);
    int sbeg = bb * cap;
    int tid = threadIdx.x;

    lcnt[tid] = 0;
    __syncthreads();
    for (int k = tid; k < scount; k += 512) {
        int rin = (int)(stg[sbeg + k] >> 32);
        atomicAdd(&lcnt[rin], 1);
    }
    __syncthreads();
    // exclusive scan over lcnt[0..511]
    int lane = tid & 63, wid = tid >> 6;
    int v = lcnt[tid];
    int x = v;
    #pragma unroll
    for (int d = 1; d < 64; d <<= 1) { int t = __shfl_up(x, d, 64); if (lane >= d) x += t; }
    if (lane == 63) wsum[wid] = x;
    __syncthreads();
    if (tid < 8) {
        int y = wsum[tid];
        #pragma unroll
        for (int d = 1; d < 8; d <<= 1) { int t = __shfl_up(y, d, 8); if (tid >= d) y += t; }
        wsum[tid] = y;
    }
    __syncthreads();
    int excl = ((wid > 0) ? wsum[wid - 1] : 0) + x - v;
    lcnt[tid] = excl;                       // becomes bucket-local running cursor
    if (tid < nrows) rowp[rows0 + tid] = ebase + excl;
    __syncthreads();
    for (int k = tid; k < scount; k += 512) {
        u64 rec = stg[sbeg + k];
        int rin = (int)(rec >> 32);
        int pos = ebase + atomicAdd(&lcnt[rin], 1);
        csr[pos] = (u32)rec;
    }
}

// ---------------- propagation ----------------

// Wave-per-row SpMM over a packed-bf16 source table, 16 edges in flight.
// lane = (g:2 | el:4). 4B records: src = rec & 0x1ffff,
// val_f32_bits = (rec & 0xfffe0000) >> 1  (bf16<<16 with sign 0).
// Accumulation f32; output dst16 (packed bf16) only — no dense sums.
__global__ __launch_bounds__(256)
void spmm_kernel(const int* __restrict__ rowptr, const u32* __restrict__ csr,
                 const u32* __restrict__ src16, u32* __restrict__ dst16,
                 int nrows) {
    int row = blockIdx.x * 4 + (threadIdx.x >> 6);
    if (row >= nrows) return;
    int lane = threadIdx.x & 63;
    int g = lane >> 4;
    int el = lane & 15;
    int beg = rowptr[row], end = rowptr[row + 1];
    const uint2* SB = (const uint2*)src16 + el;   // row stride = 16 uint2 (128B)
    float4 A0 = {0,0,0,0}, A1 = {0,0,0,0}, A2 = {0,0,0,0}, A3 = {0,0,0,0};
    for (int k = beg + g; k < end; k += 16) {
        u32 r0 = csr[k];
        u32 r1 = csr[k + 4];
        u32 r2 = csr[k + 8];
        u32 r3 = csr[k + 12];
        bool m1 = (k + 4) < end, m2 = (k + 8) < end, m3 = (k + 12) < end;
        int s0 = (int)(r0 & 0x1ffffu);
        int s1 = m1 ? (int)(r1 & 0x1ffffu) : 0;
        int s2 = m2 ? (int)(r2 & 0x1ffffu) : 0;
        int s3 = m3 ? (int)(r3 & 0x1ffffu) : 0;
        float v0 = __uint_as_float((r0 & 0xfffe0000u) >> 1);
        float v1 = m1 ? __uint_as_float((r1 & 0xfffe0000u) >> 1) : 0.f;
        float v2 = m2 ? __uint_as_float((r2 & 0xfffe0000u) >> 1) : 0.f;
        float v3 = m3 ? __uint_as_float((r3 & 0xfffe0000u) >> 1) : 0.f;
        uint2 w0 = SB[(size_t)s0 * 16];
        uint2 w1 = SB[(size_t)s1 * 16];
        uint2 w2 = SB[(size_t)s2 * 16];
        uint2 w3 = SB[(size_t)s3 * 16];
        A0.x += v0 * __uint_as_float(w0.x << 16);
        A0.y += v0 * __uint_as_float(w0.x & 0xffff0000u);
        A0.z += v0 * __uint_as_float(w0.y << 16);
        A0.w += v0 * __uint_as_float(w0.y & 0xffff0000u);
        A1.x += v1 * __uint_as_float(w1.x << 16);
        A1.y += v1 * __uint_as_float(w1.x & 0xffff0000u);
        A1.z += v1 * __uint_as_float(w1.y << 16);
        A1.w += v1 * __uint_as_float(w1.y & 0xffff0000u);
        A2.x += v2 * __uint_as_float(w2.x << 16);
        A2.y += v2 * __uint_as_float(w2.x & 0xffff0000u);
        A2.z += v2 * __uint_as_float(w2.y << 16);
        A2.w += v2 * __uint_as_float(w2.y & 0xffff0000u);
        A3.x += v3 * __uint_as_float(w3.x << 16);
        A3.y += v3 * __uint_as_float(w3.x & 0xffff0000u);
        A3.z += v3 * __uint_as_float(w3.y << 16);
        A3.w += v3 * __uint_as_float(w3.y & 0xffff0000u);
    }
    float4 a;
    a.x = (A0.x + A1.x) + (A2.x + A3.x);
    a.y = (A0.y + A1.y) + (A2.y + A3.y);
    a.z = (A0.z + A1.z) + (A2.z + A3.z);
    a.w = (A0.w + A1.w) + (A2.w + A3.w);
    a.x += __shfl_xor(a.x, 16, 64); a.x += __shfl_xor(a.x, 32, 64);
    a.y += __shfl_xor(a.y, 16, 64); a.y += __shfl_xor(a.y, 32, 64);
    a.z += __shfl_xor(a.z, 16, 64); a.z += __shfl_xor(a.z, 32, 64);
    a.w += __shfl_xor(a.w, 16, 64); a.w += __shfl_xor(a.w, 32, 64);
    if (g == 0) {
        ((uint2*)dst16)[(size_t)row * 16 + el] =
            make_uint2(pack2_bf16(a.x, a.y), pack2_bf16(a.z, a.w));
    }
}

// Final score: gather orig f32 + 3 bf16 layer rows per side for sampled pairs,
// sum, dot, scale. 16 lanes per pair.
__global__ __launch_bounds__(256)
void score_kernel(const float* __restrict__ user_emb, const float* __restrict__ item_emb,
                  const u32* __restrict__ eu1, const u32* __restrict__ eu2,
                  const u32* __restrict__ eu3,
                  const u32* __restrict__ ei1, const u32* __restrict__ ei2,
                  const u32* __restrict__ ei3,
                  const int* __restrict__ users, const int* __restrict__ items,
                  float* __restrict__ out, int B, float inv2) {
    int gid = blockIdx.x * blockDim.x + threadIdx.x;
    int b = gid >> 4;
    int lane = gid & 15;
    if (b >= B) return;
    int u = users[b], it = items[b];

    float4 su = ((const float4*)(user_emb + (size_t)u * D))[lane];
    uint2 p1 = ((const uint2*)eu1)[(size_t)u * 16 + lane];
    uint2 p2 = ((const uint2*)eu2)[(size_t)u * 16 + lane];
    uint2 p3 = ((const uint2*)eu3)[(size_t)u * 16 + lane];
    su.x += __uint_as_float(p1.x << 16) + __uint_as_float(p2.x << 16) + __uint_as_float(p3.x << 16);
    su.y += __uint_as_float(p1.x & 0xffff0000u) + __uint_as_float(p2.x & 0xffff0000u) + __uint_as_float(p3.x & 0xffff0000u);
    su.z += __uint_as_float(p1.y << 16) + __uint_as_float(p2.y << 16) + __uint_as_float(p3.y << 16);
    su.w += __uint_as_float(p1.y & 0xffff0000u) + __uint_as_float(p2.y & 0xffff0000u) + __uint_as_float(p3.y & 0xffff0000u);

    float4 si = ((const float4*)(item_emb + (size_t)it * D))[lane];
    uint2 q1 = ((const uint2*)ei1)[(size_t)it * 16 + lane];
    uint2 q2 = ((const uint2*)ei2)[(size_t)it * 16 + lane];
    uint2 q3 = ((const uint2*)ei3)[(size_t)it * 16 + lane];
    si.x += __uint_as_float(q1.x << 16) + __uint_as_float(q2.x << 16) + __uint_as_float(q3.x << 16);
    si.y += __uint_as_float(q1.x & 0xffff0000u) + __uint_as_float(q2.x & 0xffff0000u) + __uint_as_float(q3.x & 0xffff0000u);
    si.z += __uint_as_float(q1.y << 16) + __uint_as_float(q2.y << 16) + __uint_as_float(q3.y << 16);
    si.w += __uint_as_float(q1.y & 0xffff0000u) + __uint_as_float(q2.y & 0xffff0000u) + __uint_as_float(q3.y & 0xffff0000u);

    float d = su.x * si.x + su.y * si.y + su.z * si.z + su.w * si.w;
    #pragma unroll
    for (int m = 1; m < 16; m <<= 1) d += __shfl_xor(d, m, 64);
    if (lane == 0) out[b] = d * inv2;
}

// ---------------- launch ----------------

extern "C" void kernel_launch(void* const* d_in, const int* in_sizes, int n_in,
                              void* d_out, int out_size, void* d_ws, size_t ws_size,
                              hipStream_t stream) {
    const float* user_emb = (const float*)d_in[0];
    const float* item_emb = (const float*)d_in[1];
    const float* edge_vals = (const float*)d_in[2];
    const int* edge_u = (const int*)d_in[3];
    const int* edge_i = (const int*)d_in[4];
    const int* users = (const int*)d_in[5];
    const int* items = (const int*)d_in[6];
    float* out = (float*)d_out;

    const int U = in_sizes[0] / D;
    const int I = in_sizes[1] / D;
    const int E = in_sizes[2];
    const int B = in_sizes[5];

    const int nb_i = (I + (1 << SH_I) - 1) >> SH_I;
    const int nb_u = (U + (1 << SH_U) - 1) >> SH_U;
    const int cap_i = ((E / nb_i + E / (16 * nb_i) + 512 + 63) / 64) * 64;
    const int cap_u = ((E / nb_u + E / (16 * nb_u) + 512 + 63) / 64) * 64;

    // carve workspace (256B aligned)
    char* p = (char*)d_ws;
    size_t off = 0;
    auto alloc = [&](size_t bytes) -> char* {
        char* r = p + off;
        off = (off + bytes + 255) & ~(size_t)255;
        return r;
    };
    u32* ub16  = (u32*)alloc((size_t)U * (D / 2) * 4);  // packed bf16 originals
    u32* ib16  = (u32*)alloc((size_t)I * (D / 2) * 4);
    u32* eu1   = (u32*)alloc((size_t)U * (D / 2) * 4);  // per-layer bf16 tables
    u32* eu2   = (u32*)alloc((size_t)U * (D / 2) * 4);
    u32* eu3   = (u32*)alloc((size_t)U * (D / 2) * 4);
    u32* ei1   = (u32*)alloc((size_t)I * (D / 2) * 4);
    u32* ei2   = (u32*)alloc((size_t)I * (D / 2) * 4);
    u32* ei3   = (u32*)alloc((size_t)I * (D / 2) * 4);
    u32* csr_u = (u32*)alloc((size_t)(E + 16) * 4);
    u32* csr_i = (u32*)alloc((size_t)(E + 16) * 4);
    int* rowp_u = (int*)alloc((size_t)(U + 1) * 4);
    int* rowp_i = (int*)alloc((size_t)(I + 1) * 4);
    int* cur_i  = (int*)alloc((size_t)nb_i * 4);
    int* cur_u  = (int*)alloc((size_t)nb_u * 4);
    int* bb_i   = (int*)alloc((size_t)nb_i * 4);
    int* bb_u   = (int*)alloc((size_t)nb_u * 4);
    u64* stg_i  = (u64*)alloc((size_t)nb_i * cap_i * 8);
    u64* stg_u  = (u64*)alloc((size_t)nb_u * cap_u * 8);
    if (off > ws_size) return;    // workspace too small -> fail loudly

    // 0. convert original embeddings to packed bf16 gather tables
    cvt_bf16_kernel<<<1024, 256, 0, stream>>>((const float2*)user_emb, ub16, (long)U * (D / 2));
    cvt_bf16_kernel<<<1024, 256, 0, stream>>>((const float2*)item_emb, ib16, (long)I * (D / 2));

    // 1. CSR build (both directions)
    init_cursors_kernel<<<1, 512, 0, stream>>>(cur_i, nb_i, cap_i, cur_u, nb_u, cap_u);
    int tiles = (int)((E + TILE - 1) / TILE);
    passA_kernel<<<tiles, 512, 0, stream>>>(edge_u, edge_i, edge_vals, E,
                                            cur_i, nb_i, cur_u, nb_u, stg_i, stg_u);
    bucket_scan_kernel<<<1, 512, 0, stream>>>(cur_i, nb_i, cap_i, E, bb_i, rowp_i + I);
    bucket_scan_kernel<<<1, 512, 0, stream>>>(cur_u, nb_u, cap_u, E, bb_u, rowp_u + U);
    passB_kernel<<<nb_i + nb_u, 512, 0, stream>>>(nb_i, cap_i, I, nb_u, cap_u, U,
                                                  cur_i, cur_u, bb_i, bb_u,
                                                  stg_i, stg_u, rowp_i, rowp_u,
                                                  csr_i, csr_u);

    // 2. three propagation layers (Jacobi: both SpMMs read the old layer's bf16)
    int blk_i = (I + 3) / 4;
    int blk_u = (U + 3) / 4;
    spmm_kernel<<<blk_i, 256, 0, stream>>>(rowp_i, csr_i, ub16, ei1, I);
    spmm_kernel<<<blk_u, 256, 0, stream>>>(rowp_u, csr_u, ib16, eu1, U);
    spmm_kernel<<<blk_i, 256, 0, stream>>>(rowp_i, csr_i, eu1, ei2, I);
    spmm_kernel<<<blk_u, 256, 0, stream>>>(rowp_u, csr_u, ei1, eu2, U);
    spmm_kernel<<<blk_i, 256, 0, stream>>>(rowp_i, csr_i, eu2, ei3, I);
    spmm_kernel<<<blk_u, 256, 0, stream>>>(rowp_u, csr_u, ei2, eu3, U);

    // 3. final scores for sampled pairs: sum four layers, dot, scale by 1/16
    int blk_s = (B * 16 + 255) / 256;
    score_kernel<<<blk_s, 256, 0, stream>>>(user_emb, item_emb,
                                            eu1, eu2, eu3, ei1, ei2, ei3,
                                            users, items, out, B, 0.0625f);
}

// Round 9
// 379.351 us; speedup vs baseline: 21.6057x; 1.0925x over previous
//
#include <hip/hip_runtime.h>
#include <stdint.h>

#define D 64          // embedding dim
#define SH_I 8        // item rows per bucket = 256
#define SH_U 9        // user rows per bucket = 512
#define EPT 8         // edges per thread in passA
#define TILE 4096     // 512 threads * EPT
#define PAD 16        // staging segment alignment (records) = 128B line

typedef unsigned long long u64;
typedef unsigned int u32;

#define DUMMY64 0xFFFFFFFF00000000ull

// ---------------- bf16 helpers ----------------

__device__ __forceinline__ u32 bf16_rne(float f) {
    u32 x = __float_as_uint(f);
    return (x + 0x7fffu + ((x >> 16) & 1u)) >> 16;
}
__device__ __forceinline__ u32 pack2_bf16(float a, float b) {
    return bf16_rne(a) | (bf16_rne(b) << 16);
}

// f32 pairs -> packed bf16 (u32 holds 2 elems)
__global__ __launch_bounds__(256)
void cvt_bf16_kernel(const float2* __restrict__ src, u32* __restrict__ dst, long n2) {
    long i = (long)blockIdx.x * blockDim.x + threadIdx.x;
    long stride = (long)gridDim.x * blockDim.x;
    for (; i < n2; i += stride) {
        float2 f = src[i];
        dst[i] = pack2_bf16(f.x, f.y);
    }
}

// ---------------- CSR build ----------------
// Edge record (4B): [val_bf16_sans_sign:15 | src:17]   (val > 0 always)
// Staging record (8B): [dst_in_bucket:32][rec:32]; dummy has dst = 0xFFFFFFFF

__global__ __launch_bounds__(512)
void init_cursors_kernel(int* cur_i, int* rc_i, int nb_i, int cap_i,
                         int* cur_u, int* rc_u, int nb_u, int cap_u) {
    int t = threadIdx.x;
    if (t < nb_i) { cur_i[t] = t * cap_i; rc_i[t] = 0; }
    if (t < nb_u) { cur_u[t] = t * cap_u; rc_u[t] = 0; }
}

__global__ __launch_bounds__(512)
void passA_kernel(const int* __restrict__ eu, const int* __restrict__ ei,
                  const float* __restrict__ ev, int E,
                  int* __restrict__ cur_i, int* __restrict__ rc_i, int nb_i,
                  int* __restrict__ cur_u, int* __restrict__ rc_u, int nb_u,
                  u64* __restrict__ stg_i, u64* __restrict__ stg_u) {
    __shared__ int cnt_i[256], cnt_u[256];
    __shared__ int base_i[256], base_u[256];
    int tid = threadIdx.x;
    long tile0 = (long)blockIdx.x * TILE;
    if (tid < 256) { cnt_i[tid] = 0; cnt_u[tid] = 0; }
    __syncthreads();
    int uu[EPT], ii[EPT], lo_i[EPT], lo_u[EPT];
    u32 vv[EPT];
    #pragma unroll
    for (int j = 0; j < EPT; ++j) {
        long e = tile0 + tid + j * 512;
        if (e < E) {
            uu[j] = eu[e]; ii[j] = ei[e];
            vv[j] = bf16_rne(ev[e]) & 0x7fffu;
            lo_i[j] = atomicAdd(&cnt_i[ii[j] >> SH_I], 1);
            lo_u[j] = atomicAdd(&cnt_u[uu[j] >> SH_U], 1);
        } else {
            uu[j] = -1;
        }
    }
    __syncthreads();
    // allocate line-aligned segments; publish real counts; fill pad with dummies
    if (tid < nb_i && cnt_i[tid]) {
        int c = cnt_i[tid];
        int cp = (c + PAD - 1) & ~(PAD - 1);
        int base = atomicAdd(&cur_i[tid], cp);
        base_i[tid] = base;
        atomicAdd(&rc_i[tid], c);
        for (int z = c; z < cp; ++z) stg_i[base + z] = DUMMY64;
    }
    if (tid < nb_u && cnt_u[tid]) {
        int c = cnt_u[tid];
        int cp = (c + PAD - 1) & ~(PAD - 1);
        int base = atomicAdd(&cur_u[tid], cp);
        base_u[tid] = base;
        atomicAdd(&rc_u[tid], c);
        for (int z = c; z < cp; ++z) stg_u[base + z] = DUMMY64;
    }
    __syncthreads();
    #pragma unroll
    for (int j = 0; j < EPT; ++j) {
        if (uu[j] >= 0) {
            int bi = ii[j] >> SH_I;
            u32 rec_i = (vv[j] << 17) | (u32)uu[j];
            stg_i[base_i[bi] + lo_i[j]] =
                ((u64)(u32)(ii[j] & ((1 << SH_I) - 1)) << 32) | rec_i;
            int bu = uu[j] >> SH_U;
            u32 rec_u = (vv[j] << 17) | (u32)ii[j];
            stg_u[base_u[bu] + lo_u[j]] =
                ((u64)(u32)(uu[j] & ((1 << SH_U) - 1)) << 32) | rec_u;
        }
    }
}

// exclusive scan of per-bucket REAL counts -> CSR bucket bases; write sentinel
__global__ __launch_bounds__(512)
void bucket_scan_kernel(const int* __restrict__ rc, int nb, int E,
                        int* __restrict__ bbase, int* __restrict__ rowp_sentinel) {
    __shared__ int wsum[8];
    int tid = threadIdx.x, lane = tid & 63, wid = tid >> 6;
    int v = (tid < nb) ? rc[tid] : 0;
    int x = v;
    #pragma unroll
    for (int d = 1; d < 64; d <<= 1) { int t = __shfl_up(x, d, 64); if (lane >= d) x += t; }
    if (lane == 63) wsum[wid] = x;
    __syncthreads();
    if (tid < 8) {
        int y = wsum[tid];
        #pragma unroll
        for (int d = 1; d < 8; d <<= 1) { int t = __shfl_up(y, d, 8); if (tid >= d) y += t; }
        wsum[tid] = y;
    }
    __syncthreads();
    int excl = ((wid > 0) ? wsum[wid - 1] : 0) + x - v;
    if (tid < nb) bbase[tid] = excl;
    if (tid == 0) *rowp_sentinel = E;
}

// Per bucket: LDS row-histogram + block scan -> rowptr; place 4B recs into CSR.
// Skips dummy records (rin < 0).
__global__ __launch_bounds__(512)
void passB_kernel(int nb_i, int cap_i, int N_i,
                  int nb_u, int cap_u, int N_u,
                  const int* __restrict__ cur_i, const int* __restrict__ cur_u,
                  const int* __restrict__ bb_i, const int* __restrict__ bb_u,
                  const u64* __restrict__ stg_i, const u64* __restrict__ stg_u,
                  int* __restrict__ rowp_i, int* __restrict__ rowp_u,
                  u32* __restrict__ csr_i, u32* __restrict__ csr_u) {
    __shared__ int lcnt[512];
    __shared__ int wsum[8];
    int b = blockIdx.x;
    int dir_item = (b < nb_i);
    int bb = dir_item ? b : b - nb_i;
    int SH = dir_item ? SH_I : SH_U;
    int cap = dir_item ? cap_i : cap_u;
    int N = dir_item ? N_i : N_u;
    const u64* stg = dir_item ? stg_i : stg_u;
    int ebase = dir_item ? bb_i[bb] : bb_u[bb];
    int scount = (dir_item ? cur_i[bb] : cur_u[bb]) - bb * cap;   // incl. dummies
    int* rowp = dir_item ? rowp_i : rowp_u;
    u32* csr = dir_item ? csr_i : csr_u;

    int rows0 = bb << SH;
    int nrows = min(1 << SH, N - rows0);
    int sbeg = bb * cap;
    int tid = threadIdx.x;

    lcnt[tid] = 0;
    __syncthreads();
    for (int k = tid; k < scount; k += 512) {
        int rin = (int)(stg[sbeg + k] >> 32);
        if (rin >= 0) atomicAdd(&lcnt[rin], 1);
    }
    __syncthreads();
    // exclusive scan over lcnt[0..511]
    int lane = tid & 63, wid = tid >> 6;
    int v = lcnt[tid];
    int x = v;
    #pragma unroll
    for (int d = 1; d < 64; d <<= 1) { int t = __shfl_up(x, d, 64); if (lane >= d) x += t; }
    if (lane == 63) wsum[wid] = x;
    __syncthreads();
    if (tid < 8) {
        int y = wsum[tid];
        #pragma unroll
        for (int d = 1; d < 8; d <<= 1) { int t = __shfl_up(y, d, 8); if (tid >= d) y += t; }
        wsum[tid] = y;
    }
    __syncthreads();
    int excl = ((wid > 0) ? wsum[wid - 1] : 0) + x - v;
    lcnt[tid] = excl;                       // becomes bucket-local running cursor
    if (tid < nrows) rowp[rows0 + tid] = ebase + excl;
    __syncthreads();
    for (int k = tid; k < scount; k += 512) {
        u64 rec = stg[sbeg + k];
        int rin = (int)(rec >> 32);
        if (rin >= 0) {
            int pos = ebase + atomicAdd(&lcnt[rin], 1);
            csr[pos] = (u32)rec;
        }
    }
}

// ---------------- propagation ----------------

// Wave-per-row SpMM over a packed-bf16 source table, 16 edges in flight.
// lane = (g:2 | el:4). 4B records: src = rec & 0x1ffff,
// val_f32_bits = (rec & 0xfffe0000) >> 1  (bf16<<16 with sign 0).
// SAMPLED: row = idx[slot], output keyed by slot (for last layer).
template<int SAMPLED>
__global__ __launch_bounds__(256)
void spmm_kernel(const int* __restrict__ rowptr, const u32* __restrict__ csr,
                 const u32* __restrict__ src16, u32* __restrict__ dst16,
                 const int* __restrict__ idx, int nrows) {
    int slot = blockIdx.x * 4 + (threadIdx.x >> 6);
    if (slot >= nrows) return;
    int row = SAMPLED ? idx[slot] : slot;
    int lane = threadIdx.x & 63;
    int g = lane >> 4;
    int el = lane & 15;
    int beg = rowptr[row], end = rowptr[row + 1];
    const uint2* SB = (const uint2*)src16 + el;   // row stride = 16 uint2 (128B)
    float4 A0 = {0,0,0,0}, A1 = {0,0,0,0}, A2 = {0,0,0,0}, A3 = {0,0,0,0};
    for (int k = beg + g; k < end; k += 16) {
        u32 r0 = csr[k];
        u32 r1 = csr[k + 4];
        u32 r2 = csr[k + 8];
        u32 r3 = csr[k + 12];
        bool m1 = (k + 4) < end, m2 = (k + 8) < end, m3 = (k + 12) < end;
        int s0 = (int)(r0 & 0x1ffffu);
        int s1 = m1 ? (int)(r1 & 0x1ffffu) : 0;
        int s2 = m2 ? (int)(r2 & 0x1ffffu) : 0;
        int s3 = m3 ? (int)(r3 & 0x1ffffu) : 0;
        float v0 = __uint_as_float((r0 & 0xfffe0000u) >> 1);
        float v1 = m1 ? __uint_as_float((r1 & 0xfffe0000u) >> 1) : 0.f;
        float v2 = m2 ? __uint_as_float((r2 & 0xfffe0000u) >> 1) : 0.f;
        float v3 = m3 ? __uint_as_float((r3 & 0xfffe0000u) >> 1) : 0.f;
        uint2 w0 = SB[(size_t)s0 * 16];
        uint2 w1 = SB[(size_t)s1 * 16];
        uint2 w2 = SB[(size_t)s2 * 16];
        uint2 w3 = SB[(size_t)s3 * 16];
        A0.x += v0 * __uint_as_float(w0.x << 16);
        A0.y += v0 * __uint_as_float(w0.x & 0xffff0000u);
        A0.z += v0 * __uint_as_float(w0.y << 16);
        A0.w += v0 * __uint_as_float(w0.y & 0xffff0000u);
        A1.x += v1 * __uint_as_float(w1.x << 16);
        A1.y += v1 * __uint_as_float(w1.x & 0xffff0000u);
        A1.z += v1 * __uint_as_float(w1.y << 16);
        A1.w += v1 * __uint_as_float(w1.y & 0xffff0000u);
        A2.x += v2 * __uint_as_float(w2.x << 16);
        A2.y += v2 * __uint_as_float(w2.x & 0xffff0000u);
        A2.z += v2 * __uint_as_float(w2.y << 16);
        A2.w += v2 * __uint_as_float(w2.y & 0xffff0000u);
        A3.x += v3 * __uint_as_float(w3.x << 16);
        A3.y += v3 * __uint_as_float(w3.x & 0xffff0000u);
        A3.z += v3 * __uint_as_float(w3.y << 16);
        A3.w += v3 * __uint_as_float(w3.y & 0xffff0000u);
    }
    float4 a;
    a.x = (A0.x + A1.x) + (A2.x + A3.x);
    a.y = (A0.y + A1.y) + (A2.y + A3.y);
    a.z = (A0.z + A1.z) + (A2.z + A3.z);
    a.w = (A0.w + A1.w) + (A2.w + A3.w);
    a.x += __shfl_xor(a.x, 16, 64); a.x += __shfl_xor(a.x, 32, 64);
    a.y += __shfl_xor(a.y, 16, 64); a.y += __shfl_xor(a.y, 32, 64);
    a.z += __shfl_xor(a.z, 16, 64); a.z += __shfl_xor(a.z, 32, 64);
    a.w += __shfl_xor(a.w, 16, 64); a.w += __shfl_xor(a.w, 32, 64);
    if (g == 0) {
        ((uint2*)dst16)[(size_t)slot * 16 + el] =
            make_uint2(pack2_bf16(a.x, a.y), pack2_bf16(a.z, a.w));
    }
}

// Final score: per sampled pair, sum orig f32 + e1,e2 (by id) + e3 (by slot),
// dot, scale. 16 lanes per pair.
__global__ __launch_bounds__(256)
void score_kernel(const float* __restrict__ user_emb, const float* __restrict__ item_emb,
                  const u32* __restrict__ eu1, const u32* __restrict__ eu2,
                  const u32* __restrict__ eu3s,
                  const u32* __restrict__ ei1, const u32* __restrict__ ei2,
                  const u32* __restrict__ ei3s,
                  const int* __restrict__ users, const int* __restrict__ items,
                  float* __restrict__ out, int B, float inv2) {
    int gid = blockIdx.x * blockDim.x + threadIdx.x;
    int b = gid >> 4;
    int lane = gid & 15;
    if (b >= B) return;
    int u = users[b], it = items[b];

    float4 su = ((const float4*)(user_emb + (size_t)u * D))[lane];
    uint2 p1 = ((const uint2*)eu1)[(size_t)u * 16 + lane];
    uint2 p2 = ((const uint2*)eu2)[(size_t)u * 16 + lane];
    uint2 p3 = ((const uint2*)eu3s)[(size_t)b * 16 + lane];
    su.x += __uint_as_float(p1.x << 16) + __uint_as_float(p2.x << 16) + __uint_as_float(p3.x << 16);
    su.y += __uint_as_float(p1.x & 0xffff0000u) + __uint_as_float(p2.x & 0xffff0000u) + __uint_as_float(p3.x & 0xffff0000u);
    su.z += __uint_as_float(p1.y << 16) + __uint_as_float(p2.y << 16) + __uint_as_float(p3.y << 16);
    su.w += __uint_as_float(p1.y & 0xffff0000u) + __uint_as_float(p2.y & 0xffff0000u) + __uint_as_float(p3.y & 0xffff0000u);

    float4 si = ((const float4*)(item_emb + (size_t)it * D))[lane];
    uint2 q1 = ((const uint2*)ei1)[(size_t)it * 16 + lane];
    uint2 q2 = ((const uint2*)ei2)[(size_t)it * 16 + lane];
    uint2 q3 = ((const uint2*)ei3s)[(size_t)b * 16 + lane];
    si.x += __uint_as_float(q1.x << 16) + __uint_as_float(q2.x << 16) + __uint_as_float(q3.x << 16);
    si.y += __uint_as_float(q1.x & 0xffff0000u) + __uint_as_float(q2.x & 0xffff0000u) + __uint_as_float(q3.x & 0xffff0000u);
    si.z += __uint_as_float(q1.y << 16) + __uint_as_float(q2.y << 16) + __uint_as_float(q3.y << 16);
    si.w += __uint_as_float(q1.y & 0xffff0000u) + __uint_as_float(q2.y & 0xffff0000u) + __uint_as_float(q3.y & 0xffff0000u);

    float d = su.x * si.x + su.y * si.y + su.z * si.z + su.w * si.w;
    #pragma unroll
    for (int m = 1; m < 16; m <<= 1) d += __shfl_xor(d, m, 64);
    if (lane == 0) out[b] = d * inv2;
}

// ---------------- launch ----------------

extern "C" void kernel_launch(void* const* d_in, const int* in_sizes, int n_in,
                              void* d_out, int out_size, void* d_ws, size_t ws_size,
                              hipStream_t stream) {
    const float* user_emb = (const float*)d_in[0];
    const float* item_emb = (const float*)d_in[1];
    const float* edge_vals = (const float*)d_in[2];
    const int* edge_u = (const int*)d_in[3];
    const int* edge_i = (const int*)d_in[4];
    const int* users = (const int*)d_in[5];
    const int* items = (const int*)d_in[6];
    float* out = (float*)d_out;

    const int U = in_sizes[0] / D;
    const int I = in_sizes[1] / D;
    const int E = in_sizes[2];
    const int B = in_sizes[5];

    const int nb_i = (I + (1 << SH_I) - 1) >> SH_I;
    const int nb_u = (U + (1 << SH_U) - 1) >> SH_U;
    const int tiles = (E + TILE - 1) / TILE;
    // cap includes expected alignment padding (~tiles*PAD/2 per bucket) + slack
    const int cap_i = ((E / nb_i + tiles * 9 + 1536 + 63) / 64) * 64;
    const int cap_u = ((E / nb_u + tiles * 9 + 1536 + 63) / 64) * 64;

    // carve workspace (256B aligned)
    char* p = (char*)d_ws;
    size_t off = 0;
    auto alloc = [&](size_t bytes) -> char* {
        char* r = p + off;
        off = (off + bytes + 255) & ~(size_t)255;
        return r;
    };
    u32* ub16  = (u32*)alloc((size_t)U * (D / 2) * 4);  // packed bf16 originals
    u32* ib16  = (u32*)alloc((size_t)I * (D / 2) * 4);
    u32* eu1   = (u32*)alloc((size_t)U * (D / 2) * 4);  // dense layer-1/2 tables
    u32* eu2   = (u32*)alloc((size_t)U * (D / 2) * 4);
    u32* ei1   = (u32*)alloc((size_t)I * (D / 2) * 4);
    u32* ei2   = (u32*)alloc((size_t)I * (D / 2) * 4);
    u32* eu3s  = (u32*)alloc((size_t)B * (D / 2) * 4);  // sampled layer-3 (by slot)
    u32* ei3s  = (u32*)alloc((size_t)B * (D / 2) * 4);
    u32* csr_u = (u32*)alloc((size_t)(E + 16) * 4);
    u32* csr_i = (u32*)alloc((size_t)(E + 16) * 4);
    int* rowp_u = (int*)alloc((size_t)(U + 1) * 4);
    int* rowp_i = (int*)alloc((size_t)(I + 1) * 4);
    int* cur_i  = (int*)alloc((size_t)nb_i * 4);
    int* cur_u  = (int*)alloc((size_t)nb_u * 4);
    int* rc_i   = (int*)alloc((size_t)nb_i * 4);
    int* rc_u   = (int*)alloc((size_t)nb_u * 4);
    int* bb_i   = (int*)alloc((size_t)nb_i * 4);
    int* bb_u   = (int*)alloc((size_t)nb_u * 4);
    u64* stg_i  = (u64*)alloc((size_t)nb_i * cap_i * 8);
    u64* stg_u  = (u64*)alloc((size_t)nb_u * cap_u * 8);
    if (off > ws_size) return;    // workspace too small -> fail loudly

    // 0. convert original embeddings to packed bf16 gather tables
    cvt_bf16_kernel<<<1024, 256, 0, stream>>>((const float2*)user_emb, ub16, (long)U * (D / 2));
    cvt_bf16_kernel<<<1024, 256, 0, stream>>>((const float2*)item_emb, ib16, (long)I * (D / 2));

    // 1. CSR build (both directions)
    init_cursors_kernel<<<1, 512, 0, stream>>>(cur_i, rc_i, nb_i, cap_i,
                                               cur_u, rc_u, nb_u, cap_u);
    passA_kernel<<<tiles, 512, 0, stream>>>(edge_u, edge_i, edge_vals, E,
                                            cur_i, rc_i, nb_i, cur_u, rc_u, nb_u,
                                            stg_i, stg_u);
    bucket_scan_kernel<<<1, 512, 0, stream>>>(rc_i, nb_i, E, bb_i, rowp_i + I);
    bucket_scan_kernel<<<1, 512, 0, stream>>>(rc_u, nb_u, E, bb_u, rowp_u + U);
    passB_kernel<<<nb_i + nb_u, 512, 0, stream>>>(nb_i, cap_i, I, nb_u, cap_u, U,
                                                  cur_i, cur_u, bb_i, bb_u,
                                                  stg_i, stg_u, rowp_i, rowp_u,
                                                  csr_i, csr_u);

    // 2. propagation: layers 1-2 dense, layer 3 only for sampled rows
    int blk_i = (I + 3) / 4;
    int blk_u = (U + 3) / 4;
    int blk_s = (B + 3) / 4;
    spmm_kernel<0><<<blk_i, 256, 0, stream>>>(rowp_i, csr_i, ub16, ei1, nullptr, I);
    spmm_kernel<0><<<blk_u, 256, 0, stream>>>(rowp_u, csr_u, ib16, eu1, nullptr, U);
    spmm_kernel<0><<<blk_i, 256, 0, stream>>>(rowp_i, csr_i, eu1, ei2, nullptr, I);
    spmm_kernel<0><<<blk_u, 256, 0, stream>>>(rowp_u, csr_u, ei1, eu2, nullptr, U);
    spmm_kernel<1><<<blk_s, 256, 0, stream>>>(rowp_i, csr_i, eu2, ei3s, items, B);
    spmm_kernel<1><<<blk_s, 256, 0, stream>>>(rowp_u, csr_u, ei2, eu3s, users, B);

    // 3. final scores for sampled pairs: sum four layers, dot, scale by 1/16
    int blk_sc = (B * 16 + 255) / 256;
    score_kernel<<<blk_sc, 256, 0, stream>>>(user_emb, item_emb,
                                             eu1, eu2, eu3s, ei1, ei2, ei3s,
                                             users, items, out, B, 0.0625f);
}

// Round 10
// 352.097 us; speedup vs baseline: 23.2781x; 1.0774x over previous
//
#include <hip/hip_runtime.h>
#include <stdint.h>

#define D 64          // embedding dim
#define SH_I 8        // item rows per bucket = 256
#define SH_U 9        // user rows per bucket = 512
#define EPT 8         // edges per thread in passA
#define TILE 4096     // 512 threads * EPT
#define PAD 8         // staging segment alignment (records) = 64B sector

typedef unsigned long long u64;
typedef unsigned int u32;

#define DUMMY64 0xFFFFFFFF00000000ull

// ---------------- bf16 helpers ----------------

__device__ __forceinline__ u32 bf16_rne(float f) {
    u32 x = __float_as_uint(f);
    return (x + 0x7fffu + ((x >> 16) & 1u)) >> 16;
}
__device__ __forceinline__ u32 pack2_bf16(float a, float b) {
    return bf16_rne(a) | (bf16_rne(b) << 16);
}

// f32 pairs -> packed bf16 (u32 holds 2 elems)
__global__ __launch_bounds__(256)
void cvt_bf16_kernel(const float2* __restrict__ src, u32* __restrict__ dst, long n2) {
    long i = (long)blockIdx.x * blockDim.x + threadIdx.x;
    long stride = (long)gridDim.x * blockDim.x;
    for (; i < n2; i += stride) {
        float2 f = src[i];
        dst[i] = pack2_bf16(f.x, f.y);
    }
}

// ---------------- scan helpers ----------------

__device__ __forceinline__ int excl_scan_512t(int v, int* wsum) {
    int tid = threadIdx.x, lane = tid & 63, wid = tid >> 6;
    int x = v;
    #pragma unroll
    for (int d = 1; d < 64; d <<= 1) { int t = __shfl_up(x, d, 64); if (lane >= d) x += t; }
    if (lane == 63) wsum[wid] = x;
    __syncthreads();
    if (tid < 8) {
        int y = wsum[tid];
        #pragma unroll
        for (int d = 1; d < 8; d <<= 1) { int t = __shfl_up(y, d, 8); if (tid >= d) y += t; }
        wsum[tid] = y;
    }
    __syncthreads();
    return ((wid > 0) ? wsum[wid - 1] : 0) + x - v;
}

__device__ __forceinline__ int excl_scan_1024t(int v, int* wsum16) {
    int tid = threadIdx.x, lane = tid & 63, wid = tid >> 6;
    int x = v;
    #pragma unroll
    for (int d = 1; d < 64; d <<= 1) { int t = __shfl_up(x, d, 64); if (lane >= d) x += t; }
    if (lane == 63) wsum16[wid] = x;
    __syncthreads();
    if (tid < 16) {
        int y = wsum16[tid];
        #pragma unroll
        for (int d = 1; d < 16; d <<= 1) { int t = __shfl_up(y, d, 16); if (tid >= d) y += t; }
        wsum16[tid] = y;
    }
    __syncthreads();
    return ((wid > 0) ? wsum16[wid - 1] : 0) + x - v;
}

// ---------------- CSR build ----------------
// Edge record (4B): [val_bf16_sans_sign:15 | src:17]   (val > 0 always)
// Staging record (8B): [dst_in_bucket:32][rec:32]; dummy has dst = 0xFFFFFFFF

__global__ __launch_bounds__(512)
void init_cursors_kernel(int* cur_i, int* rc_i, int nb_i, int cap_i,
                         int* cur_u, int* rc_u, int nb_u, int cap_u) {
    int t = threadIdx.x;
    if (t < nb_i) { cur_i[t] = t * cap_i; rc_i[t] = 0; }
    if (t < nb_u) { cur_u[t] = t * cap_u; rc_u[t] = 0; }
}

// LDS-sorted binning: histogram -> LDS scan -> LDS scatter -> per-bucket
// burst copy to 64B-aligned global segments (full-sector writes, amp ~1).
__global__ __launch_bounds__(512)
void passA_kernel(const int* __restrict__ eu, const int* __restrict__ ei,
                  const float* __restrict__ ev, int E,
                  int* __restrict__ cur_i, int* __restrict__ rc_i,
                  int* __restrict__ cur_u, int* __restrict__ rc_u,
                  u64* __restrict__ stg_i, u64* __restrict__ stg_u) {
    __shared__ u64 stage[TILE];            // 32KB sorted staging
    __shared__ int cnt[256], loffs[256], gbase[256];
    __shared__ int wsum[8];
    int tid = threadIdx.x;
    long tile0 = (long)blockIdx.x * TILE;
    int uu[EPT], ii[EPT], lo[EPT];
    u32 vv[EPT];
    #pragma unroll
    for (int j = 0; j < EPT; ++j) {
        long e = tile0 + tid + j * 512;
        if (e < E) {
            uu[j] = eu[e]; ii[j] = ei[e];
            vv[j] = bf16_rne(ev[e]) & 0x7fffu;
        } else {
            uu[j] = -1;
        }
    }

    // ---------- direction: dst = item (bucket = ii>>SH_I, src = uu) ----------
    if (tid < 256) cnt[tid] = 0;
    __syncthreads();
    #pragma unroll
    for (int j = 0; j < EPT; ++j)
        if (uu[j] >= 0) lo[j] = atomicAdd(&cnt[ii[j] >> SH_I], 1);
    __syncthreads();
    {
        int c = (tid < 256) ? cnt[tid] : 0;
        int excl = excl_scan_512t(c, wsum);
        if (tid < 256) {
            loffs[tid] = excl;
            if (c) {
                int cp = (c + PAD - 1) & ~(PAD - 1);
                gbase[tid] = atomicAdd(&cur_i[tid], cp);
                atomicAdd(&rc_i[tid], c);
            }
        }
    }
    __syncthreads();
    #pragma unroll
    for (int j = 0; j < EPT; ++j) {
        if (uu[j] >= 0) {
            int b = ii[j] >> SH_I;
            u32 rec = (vv[j] << 17) | (u32)uu[j];
            stage[loffs[b] + lo[j]] =
                ((u64)(u32)(ii[j] & ((1 << SH_I) - 1)) << 32) | rec;
        }
    }
    __syncthreads();
    {
        int w = tid >> 6, lane = tid & 63;
        for (int b = w; b < 256; b += 8) {
            int c = cnt[b];
            if (!c) continue;
            int cp = (c + PAD - 1) & ~(PAD - 1);
            int lb = loffs[b];
            long gb = gbase[b];
            for (int r = lane; r < cp; r += 64)
                stg_i[gb + r] = (r < c) ? stage[lb + r] : DUMMY64;
        }
    }
    __syncthreads();

    // ---------- direction: dst = user (bucket = uu>>SH_U, src = ii) ----------
    if (tid < 256) cnt[tid] = 0;
    __syncthreads();
    #pragma unroll
    for (int j = 0; j < EPT; ++j)
        if (uu[j] >= 0) lo[j] = atomicAdd(&cnt[uu[j] >> SH_U], 1);
    __syncthreads();
    {
        int c = (tid < 256) ? cnt[tid] : 0;
        int excl = excl_scan_512t(c, wsum);
        if (tid < 256) {
            loffs[tid] = excl;
            if (c) {
                int cp = (c + PAD - 1) & ~(PAD - 1);
                gbase[tid] = atomicAdd(&cur_u[tid], cp);
                atomicAdd(&rc_u[tid], c);
            }
        }
    }
    __syncthreads();
    #pragma unroll
    for (int j = 0; j < EPT; ++j) {
        if (uu[j] >= 0) {
            int b = uu[j] >> SH_U;
            u32 rec = (vv[j] << 17) | (u32)ii[j];
            stage[loffs[b] + lo[j]] =
                ((u64)(u32)(uu[j] & ((1 << SH_U) - 1)) << 32) | rec;
        }
    }
    __syncthreads();
    {
        int w = tid >> 6, lane = tid & 63;
        for (int b = w; b < 256; b += 8) {
            int c = cnt[b];
            if (!c) continue;
            int cp = (c + PAD - 1) & ~(PAD - 1);
            int lb = loffs[b];
            long gb = gbase[b];
            for (int r = lane; r < cp; r += 64)
                stg_u[gb + r] = (r < c) ? stage[lb + r] : DUMMY64;
        }
    }
}

// exclusive scan of per-bucket REAL counts -> CSR bucket bases; write sentinel
__global__ __launch_bounds__(512)
void bucket_scan_kernel(const int* __restrict__ rc, int nb, int E,
                        int* __restrict__ bbase, int* __restrict__ rowp_sentinel) {
    __shared__ int wsum[8];
    int tid = threadIdx.x;
    int v = (tid < nb) ? rc[tid] : 0;
    int excl = excl_scan_512t(v, wsum);
    if (tid < nb) bbase[tid] = excl;
    if (tid == 0) *rowp_sentinel = E;
}

// Per bucket: LDS row-histogram + block scan -> rowptr; place 4B recs into CSR.
// 1024 threads, uint4 loads (2 records each). Skips dummies (rin < 0).
__global__ __launch_bounds__(1024)
void passB_kernel(int nb_i, int cap_i, int N_i,
                  int nb_u, int cap_u, int N_u,
                  const int* __restrict__ cur_i, const int* __restrict__ cur_u,
                  const int* __restrict__ bb_i, const int* __restrict__ bb_u,
                  const u64* __restrict__ stg_i, const u64* __restrict__ stg_u,
                  int* __restrict__ rowp_i, int* __restrict__ rowp_u,
                  u32* __restrict__ csr_i, u32* __restrict__ csr_u) {
    __shared__ int lcnt[512];
    __shared__ int wsum[16];
    int b = blockIdx.x;
    int dir_item = (b < nb_i);
    int bb = dir_item ? b : b - nb_i;
    int SH = dir_item ? SH_I : SH_U;
    int cap = dir_item ? cap_i : cap_u;
    int N = dir_item ? N_i : N_u;
    const u64* stg = dir_item ? stg_i : stg_u;
    int ebase = dir_item ? bb_i[bb] : bb_u[bb];
    int scount = (dir_item ? cur_i[bb] : cur_u[bb]) - bb * cap;   // incl. dummies
    int* rowp = dir_item ? rowp_i : rowp_u;
    u32* csr = dir_item ? csr_i : csr_u;

    int rows0 = bb << SH;
    int nrows = min(1 << SH, N - rows0);
    int tid = threadIdx.x;
    const uint4* stg4 = (const uint4*)(stg + (size_t)bb * cap);
    int npair = scount >> 1;                 // scount is a multiple of PAD=8

    if (tid < 512) lcnt[tid] = 0;
    __syncthreads();
    for (int k = tid; k < npair; k += 1024) {
        uint4 w = stg4[k];
        if ((int)w.y >= 0) atomicAdd(&lcnt[(int)w.y], 1);
        if ((int)w.w >= 0) atomicAdd(&lcnt[(int)w.w], 1);
    }
    __syncthreads();
    int v = (tid < 512) ? lcnt[tid] : 0;
    int excl = excl_scan_1024t(v, wsum);
    if (tid < 512) lcnt[tid] = excl;         // becomes bucket-local running cursor
    if (tid < nrows) rowp[rows0 + tid] = ebase + excl;
    __syncthreads();
    for (int k = tid; k < npair; k += 1024) {
        uint4 w = stg4[k];
        if ((int)w.y >= 0) {
            int pos = ebase + atomicAdd(&lcnt[(int)w.y], 1);
            csr[pos] = w.x;
        }
        if ((int)w.w >= 0) {
            int pos = ebase + atomicAdd(&lcnt[(int)w.w], 1);
            csr[pos] = w.z;
        }
    }
}

// ---------------- propagation ----------------

// Wave-per-row SpMM over a packed-bf16 source table, 16 edges in flight.
// lane = (g:2 | el:4). 4B records: src = rec & 0x1ffff,
// val_f32_bits = (rec & 0xfffe0000) >> 1  (bf16<<16 with sign 0).
// SAMPLED: row = idx[slot], output keyed by slot (for last layer).
template<int SAMPLED>
__global__ __launch_bounds__(256)
void spmm_kernel(const int* __restrict__ rowptr, const u32* __restrict__ csr,
                 const u32* __restrict__ src16, u32* __restrict__ dst16,
                 const int* __restrict__ idx, int nrows) {
    int slot = blockIdx.x * 4 + (threadIdx.x >> 6);
    if (slot >= nrows) return;
    int row = SAMPLED ? idx[slot] : slot;
    int lane = threadIdx.x & 63;
    int g = lane >> 4;
    int el = lane & 15;
    int beg = rowptr[row], end = rowptr[row + 1];
    const uint2* SB = (const uint2*)src16 + el;   // row stride = 16 uint2 (128B)
    float4 A0 = {0,0,0,0}, A1 = {0,0,0,0}, A2 = {0,0,0,0}, A3 = {0,0,0,0};
    for (int k = beg + g; k < end; k += 16) {
        u32 r0 = csr[k];
        u32 r1 = csr[k + 4];
        u32 r2 = csr[k + 8];
        u32 r3 = csr[k + 12];
        bool m1 = (k + 4) < end, m2 = (k + 8) < end, m3 = (k + 12) < end;
        int s0 = (int)(r0 & 0x1ffffu);
        int s1 = m1 ? (int)(r1 & 0x1ffffu) : 0;
        int s2 = m2 ? (int)(r2 & 0x1ffffu) : 0;
        int s3 = m3 ? (int)(r3 & 0x1ffffu) : 0;
        float v0 = __uint_as_float((r0 & 0xfffe0000u) >> 1);
        float v1 = m1 ? __uint_as_float((r1 & 0xfffe0000u) >> 1) : 0.f;
        float v2 = m2 ? __uint_as_float((r2 & 0xfffe0000u) >> 1) : 0.f;
        float v3 = m3 ? __uint_as_float((r3 & 0xfffe0000u) >> 1) : 0.f;
        uint2 w0 = SB[(size_t)s0 * 16];
        uint2 w1 = SB[(size_t)s1 * 16];
        uint2 w2 = SB[(size_t)s2 * 16];
        uint2 w3 = SB[(size_t)s3 * 16];
        A0.x += v0 * __uint_as_float(w0.x << 16);
        A0.y += v0 * __uint_as_float(w0.x & 0xffff0000u);
        A0.z += v0 * __uint_as_float(w0.y << 16);
        A0.w += v0 * __uint_as_float(w0.y & 0xffff0000u);
        A1.x += v1 * __uint_as_float(w1.x << 16);
        A1.y += v1 * __uint_as_float(w1.x & 0xffff0000u);
        A1.z += v1 * __uint_as_float(w1.y << 16);
        A1.w += v1 * __uint_as_float(w1.y & 0xffff0000u);
        A2.x += v2 * __uint_as_float(w2.x << 16);
        A2.y += v2 * __uint_as_float(w2.x & 0xffff0000u);
        A2.z += v2 * __uint_as_float(w2.y << 16);
        A2.w += v2 * __uint_as_float(w2.y & 0xffff0000u);
        A3.x += v3 * __uint_as_float(w3.x << 16);
        A3.y += v3 * __uint_as_float(w3.x & 0xffff0000u);
        A3.z += v3 * __uint_as_float(w3.y << 16);
        A3.w += v3 * __uint_as_float(w3.y & 0xffff0000u);
    }
    float4 a;
    a.x = (A0.x + A1.x) + (A2.x + A3.x);
    a.y = (A0.y + A1.y) + (A2.y + A3.y);
    a.z = (A0.z + A1.z) + (A2.z + A3.z);
    a.w = (A0.w + A1.w) + (A2.w + A3.w);
    a.x += __shfl_xor(a.x, 16, 64); a.x += __shfl_xor(a.x, 32, 64);
    a.y += __shfl_xor(a.y, 16, 64); a.y += __shfl_xor(a.y, 32, 64);
    a.z += __shfl_xor(a.z, 16, 64); a.z += __shfl_xor(a.z, 32, 64);
    a.w += __shfl_xor(a.w, 16, 64); a.w += __shfl_xor(a.w, 32, 64);
    if (g == 0) {
        ((uint2*)dst16)[(size_t)slot * 16 + el] =
            make_uint2(pack2_bf16(a.x, a.y), pack2_bf16(a.z, a.w));
    }
}

// Final score: per sampled pair, sum orig f32 + e1,e2 (by id) + e3 (by slot),
// dot, scale. 16 lanes per pair.
__global__ __launch_bounds__(256)
void score_kernel(const float* __restrict__ user_emb, const float* __restrict__ item_emb,
                  const u32* __restrict__ eu1, const u32* __restrict__ eu2,
                  const u32* __restrict__ eu3s,
                  const u32* __restrict__ ei1, const u32* __restrict__ ei2,
                  const u32* __restrict__ ei3s,
                  const int* __restrict__ users, const int* __restrict__ items,
                  float* __restrict__ out, int B, float inv2) {
    int gid = blockIdx.x * blockDim.x + threadIdx.x;
    int b = gid >> 4;
    int lane = gid & 15;
    if (b >= B) return;
    int u = users[b], it = items[b];

    float4 su = ((const float4*)(user_emb + (size_t)u * D))[lane];
    uint2 p1 = ((const uint2*)eu1)[(size_t)u * 16 + lane];
    uint2 p2 = ((const uint2*)eu2)[(size_t)u * 16 + lane];
    uint2 p3 = ((const uint2*)eu3s)[(size_t)b * 16 + lane];
    su.x += __uint_as_float(p1.x << 16) + __uint_as_float(p2.x << 16) + __uint_as_float(p3.x << 16);
    su.y += __uint_as_float(p1.x & 0xffff0000u) + __uint_as_float(p2.x & 0xffff0000u) + __uint_as_float(p3.x & 0xffff0000u);
    su.z += __uint_as_float(p1.y << 16) + __uint_as_float(p2.y << 16) + __uint_as_float(p3.y << 16);
    su.w += __uint_as_float(p1.y & 0xffff0000u) + __uint_as_float(p2.y & 0xffff0000u) + __uint_as_float(p3.y & 0xffff0000u);

    float4 si = ((const float4*)(item_emb + (size_t)it * D))[lane];
    uint2 q1 = ((const uint2*)ei1)[(size_t)it * 16 + lane];
    uint2 q2 = ((const uint2*)ei2)[(size_t)it * 16 + lane];
    uint2 q3 = ((const uint2*)ei3s)[(size_t)b * 16 + lane];
    si.x += __uint_as_float(q1.x << 16) + __uint_as_float(q2.x << 16) + __uint_as_float(q3.x << 16);
    si.y += __uint_as_float(q1.x & 0xffff0000u) + __uint_as_float(q2.x & 0xffff0000u) + __uint_as_float(q3.x & 0xffff0000u);
    si.z += __uint_as_float(q1.y << 16) + __uint_as_float(q2.y << 16) + __uint_as_float(q3.y << 16);
    si.w += __uint_as_float(q1.y & 0xffff0000u) + __uint_as_float(q2.y & 0xffff0000u) + __uint_as_float(q3.y & 0xffff0000u);

    float d = su.x * si.x + su.y * si.y + su.z * si.z + su.w * si.w;
    #pragma unroll
    for (int m = 1; m < 16; m <<= 1) d += __shfl_xor(d, m, 64);
    if (lane == 0) out[b] = d * inv2;
}

// ---------------- launch ----------------

extern "C" void kernel_launch(void* const* d_in, const int* in_sizes, int n_in,
                              void* d_out, int out_size, void* d_ws, size_t ws_size,
                              hipStream_t stream) {
    const float* user_emb = (const float*)d_in[0];
    const float* item_emb = (const float*)d_in[1];
    const float* edge_vals = (const float*)d_in[2];
    const int* edge_u = (const int*)d_in[3];
    const int* edge_i = (const int*)d_in[4];
    const int* users = (const int*)d_in[5];
    const int* items = (const int*)d_in[6];
    float* out = (float*)d_out;

    const int U = in_sizes[0] / D;
    const int I = in_sizes[1] / D;
    const int E = in_sizes[2];
    const int B = in_sizes[5];

    const int nb_i = (I + (1 << SH_I) - 1) >> SH_I;
    const int nb_u = (U + (1 << SH_U) - 1) >> SH_U;
    const int tiles = (E + TILE - 1) / TILE;
    // cap: mean real + worst-case pad (PAD-1 per block) + variance slack
    const int cap_i = ((E / nb_i + tiles * (PAD - 1) + 1024 + 63) / 64) * 64;
    const int cap_u = ((E / nb_u + tiles * (PAD - 1) + 1024 + 63) / 64) * 64;

    // carve workspace (256B aligned)
    char* p = (char*)d_ws;
    size_t off = 0;
    auto alloc = [&](size_t bytes) -> char* {
        char* r = p + off;
        off = (off + bytes + 255) & ~(size_t)255;
        return r;
    };
    u32* ub16  = (u32*)alloc((size_t)U * (D / 2) * 4);  // packed bf16 originals
    u32* ib16  = (u32*)alloc((size_t)I * (D / 2) * 4);
    u32* eu1   = (u32*)alloc((size_t)U * (D / 2) * 4);  // dense layer-1/2 tables
    u32* eu2   = (u32*)alloc((size_t)U * (D / 2) * 4);
    u32* ei1   = (u32*)alloc((size_t)I * (D / 2) * 4);
    u32* ei2   = (u32*)alloc((size_t)I * (D / 2) * 4);
    u32* eu3s  = (u32*)alloc((size_t)B * (D / 2) * 4);  // sampled layer-3 (by slot)
    u32* ei3s  = (u32*)alloc((size_t)B * (D / 2) * 4);
    u32* csr_u = (u32*)alloc((size_t)(E + 16) * 4);
    u32* csr_i = (u32*)alloc((size_t)(E + 16) * 4);
    int* rowp_u = (int*)alloc((size_t)(U + 1) * 4);
    int* rowp_i = (int*)alloc((size_t)(I + 1) * 4);
    int* cur_i  = (int*)alloc((size_t)nb_i * 4);
    int* cur_u  = (int*)alloc((size_t)nb_u * 4);
    int* rc_i   = (int*)alloc((size_t)nb_i * 4);
    int* rc_u   = (int*)alloc((size_t)nb_u * 4);
    int* bb_i   = (int*)alloc((size_t)nb_i * 4);
    int* bb_u   = (int*)alloc((size_t)nb_u * 4);
    u64* stg_i  = (u64*)alloc((size_t)nb_i * cap_i * 8);
    u64* stg_u  = (u64*)alloc((size_t)nb_u * cap_u * 8);
    if (off > ws_size) return;    // workspace too small -> fail loudly

    // 0. convert original embeddings to packed bf16 gather tables
    cvt_bf16_kernel<<<1024, 256, 0, stream>>>((const float2*)user_emb, ub16, (long)U * (D / 2));
    cvt_bf16_kernel<<<1024, 256, 0, stream>>>((const float2*)item_emb, ib16, (long)I * (D / 2));

    // 1. CSR build (both directions)
    init_cursors_kernel<<<1, 512, 0, stream>>>(cur_i, rc_i, nb_i, cap_i,
                                               cur_u, rc_u, nb_u, cap_u);
    passA_kernel<<<tiles, 512, 0, stream>>>(edge_u, edge_i, edge_vals, E,
                                            cur_i, rc_i, cur_u, rc_u,
                                            stg_i, stg_u);
    bucket_scan_kernel<<<1, 512, 0, stream>>>(rc_i, nb_i, E, bb_i, rowp_i + I);
    bucket_scan_kernel<<<1, 512, 0, stream>>>(rc_u, nb_u, E, bb_u, rowp_u + U);
    passB_kernel<<<nb_i + nb_u, 1024, 0, stream>>>(nb_i, cap_i, I, nb_u, cap_u, U,
                                                   cur_i, cur_u, bb_i, bb_u,
                                                   stg_i, stg_u, rowp_i, rowp_u,
                                                   csr_i, csr_u);

    // 2. propagation: layers 1-2 dense, layer 3 only for sampled rows
    int blk_i = (I + 3) / 4;
    int blk_u = (U + 3) / 4;
    int blk_s = (B + 3) / 4;
    spmm_kernel<0><<<blk_i, 256, 0, stream>>>(rowp_i, csr_i, ub16, ei1, nullptr, I);
    spmm_kernel<0><<<blk_u, 256, 0, stream>>>(rowp_u, csr_u, ib16, eu1, nullptr, U);
    spmm_kernel<0><<<blk_i, 256, 0, stream>>>(rowp_i, csr_i, eu1, ei2, nullptr, I);
    spmm_kernel<0><<<blk_u, 256, 0, stream>>>(rowp_u, csr_u, ei1, eu2, nullptr, U);
    spmm_kernel<1><<<blk_s, 256, 0, stream>>>(rowp_i, csr_i, eu2, ei3s, items, B);
    spmm_kernel<1><<<blk_s, 256, 0, stream>>>(rowp_u, csr_u, ei2, eu3s, users, B);

    // 3. final scores for sampled pairs: sum four layers, dot, scale by 1/16
    int blk_sc = (B * 16 + 255) / 256;
    score_kernel<<<blk_sc, 256, 0, stream>>>(user_emb, item_emb,
                                             eu1, eu2, eu3s, ei1, ei2, ei3s,
                                             users, items, out, B, 0.0625f);
}

// Round 11
// 321.664 us; speedup vs baseline: 25.4804x; 1.0946x over previous
//
#include <hip/hip_runtime.h>
#include <stdint.h>

#define D 64          // embedding dim
#define SH_I 8        // item rows per bucket = 256
#define SH_U 9        // user rows per bucket = 512
#define EPT 8         // edges per thread in passA
#define TILE 4096     // 512 threads * EPT
#define PAD 8         // staging segment alignment (records) = 64B sector
#define SRT_CAP 18944 // LDS sorted-CSR buffer (4B recs) = 74KB

typedef unsigned long long u64;
typedef unsigned int u32;

#define DUMMY64 0xFFFFFFFF00000000ull

// ---------------- bf16 helpers ----------------

__device__ __forceinline__ u32 bf16_rne(float f) {
    u32 x = __float_as_uint(f);
    return (x + 0x7fffu + ((x >> 16) & 1u)) >> 16;
}
__device__ __forceinline__ u32 pack2_bf16(float a, float b) {
    return bf16_rne(a) | (bf16_rne(b) << 16);
}

// f32 pairs -> packed bf16 (u32 holds 2 elems)
__global__ __launch_bounds__(256)
void cvt_bf16_kernel(const float2* __restrict__ src, u32* __restrict__ dst, long n2) {
    long i = (long)blockIdx.x * blockDim.x + threadIdx.x;
    long stride = (long)gridDim.x * blockDim.x;
    for (; i < n2; i += stride) {
        float2 f = src[i];
        dst[i] = pack2_bf16(f.x, f.y);
    }
}

// ---------------- scan helpers ----------------

__device__ __forceinline__ int excl_scan_512t(int v, int* wsum) {
    int tid = threadIdx.x, lane = tid & 63, wid = tid >> 6;
    int x = v;
    #pragma unroll
    for (int d = 1; d < 64; d <<= 1) { int t = __shfl_up(x, d, 64); if (lane >= d) x += t; }
    if (lane == 63) wsum[wid] = x;
    __syncthreads();
    if (tid < 8) {
        int y = wsum[tid];
        #pragma unroll
        for (int d = 1; d < 8; d <<= 1) { int t = __shfl_up(y, d, 8); if (tid >= d) y += t; }
        wsum[tid] = y;
    }
    __syncthreads();
    return ((wid > 0) ? wsum[wid - 1] : 0) + x - v;
}

__device__ __forceinline__ int excl_scan_1024t(int v, int* wsum16) {
    int tid = threadIdx.x, lane = tid & 63, wid = tid >> 6;
    int x = v;
    #pragma unroll
    for (int d = 1; d < 64; d <<= 1) { int t = __shfl_up(x, d, 64); if (lane >= d) x += t; }
    if (lane == 63) wsum16[wid] = x;
    __syncthreads();
    if (tid < 16) {
        int y = wsum16[tid];
        #pragma unroll
        for (int d = 1; d < 16; d <<= 1) { int t = __shfl_up(y, d, 16); if (tid >= d) y += t; }
        wsum16[tid] = y;
    }
    __syncthreads();
    return ((wid > 0) ? wsum16[wid - 1] : 0) + x - v;
}

// ---------------- CSR build ----------------
// Edge record (4B): [val_bf16_sans_sign:15 | src:17]   (val > 0 always)
// Staging record (8B): [dst_in_bucket:32][rec:32]; dummy has dst = 0xFFFFFFFF

__global__ __launch_bounds__(512)
void init_cursors_kernel(int* cur_i, int* rc_i, int nb_i, int cap_i,
                         int* cur_u, int* rc_u, int nb_u, int cap_u) {
    int t = threadIdx.x;
    if (t < nb_i) { cur_i[t] = t * cap_i; rc_i[t] = 0; }
    if (t < nb_u) { cur_u[t] = t * cap_u; rc_u[t] = 0; }
}

// LDS-sorted binning: histogram -> LDS scan -> LDS scatter -> per-bucket
// burst copy to 64B-aligned global segments (full-sector writes, amp ~1).
__global__ __launch_bounds__(512)
void passA_kernel(const int* __restrict__ eu, const int* __restrict__ ei,
                  const float* __restrict__ ev, int E,
                  int* __restrict__ cur_i, int* __restrict__ rc_i,
                  int* __restrict__ cur_u, int* __restrict__ rc_u,
                  u64* __restrict__ stg_i, u64* __restrict__ stg_u) {
    __shared__ u64 stage[TILE];            // 32KB sorted staging
    __shared__ int cnt[256], loffs[256], gbase[256];
    __shared__ int wsum[8];
    int tid = threadIdx.x;
    long tile0 = (long)blockIdx.x * TILE;
    int uu[EPT], ii[EPT], lo[EPT];
    u32 vv[EPT];
    #pragma unroll
    for (int j = 0; j < EPT; ++j) {
        long e = tile0 + tid + j * 512;
        if (e < E) {
            uu[j] = eu[e]; ii[j] = ei[e];
            vv[j] = bf16_rne(ev[e]) & 0x7fffu;
        } else {
            uu[j] = -1;
        }
    }

    // ---------- direction: dst = item (bucket = ii>>SH_I, src = uu) ----------
    if (tid < 256) cnt[tid] = 0;
    __syncthreads();
    #pragma unroll
    for (int j = 0; j < EPT; ++j)
        if (uu[j] >= 0) lo[j] = atomicAdd(&cnt[ii[j] >> SH_I], 1);
    __syncthreads();
    {
        int c = (tid < 256) ? cnt[tid] : 0;
        int excl = excl_scan_512t(c, wsum);
        if (tid < 256) {
            loffs[tid] = excl;
            if (c) {
                int cp = (c + PAD - 1) & ~(PAD - 1);
                gbase[tid] = atomicAdd(&cur_i[tid], cp);
                atomicAdd(&rc_i[tid], c);
            }
        }
    }
    __syncthreads();
    #pragma unroll
    for (int j = 0; j < EPT; ++j) {
        if (uu[j] >= 0) {
            int b = ii[j] >> SH_I;
            u32 rec = (vv[j] << 17) | (u32)uu[j];
            stage[loffs[b] + lo[j]] =
                ((u64)(u32)(ii[j] & ((1 << SH_I) - 1)) << 32) | rec;
        }
    }
    __syncthreads();
    {
        int w = tid >> 6, lane = tid & 63;
        for (int b = w; b < 256; b += 8) {
            int c = cnt[b];
            if (!c) continue;
            int cp = (c + PAD - 1) & ~(PAD - 1);
            int lb = loffs[b];
            long gb = gbase[b];
            for (int r = lane; r < cp; r += 64)
                stg_i[gb + r] = (r < c) ? stage[lb + r] : DUMMY64;
        }
    }
    __syncthreads();

    // ---------- direction: dst = user (bucket = uu>>SH_U, src = ii) ----------
    if (tid < 256) cnt[tid] = 0;
    __syncthreads();
    #pragma unroll
    for (int j = 0; j < EPT; ++j)
        if (uu[j] >= 0) lo[j] = atomicAdd(&cnt[uu[j] >> SH_U], 1);
    __syncthreads();
    {
        int c = (tid < 256) ? cnt[tid] : 0;
        int excl = excl_scan_512t(c, wsum);
        if (tid < 256) {
            loffs[tid] = excl;
            if (c) {
                int cp = (c + PAD - 1) & ~(PAD - 1);
                gbase[tid] = atomicAdd(&cur_u[tid], cp);
                atomicAdd(&rc_u[tid], c);
            }
        }
    }
    __syncthreads();
    #pragma unroll
    for (int j = 0; j < EPT; ++j) {
        if (uu[j] >= 0) {
            int b = uu[j] >> SH_U;
            u32 rec = (vv[j] << 17) | (u32)ii[j];
            stage[loffs[b] + lo[j]] =
                ((u64)(u32)(uu[j] & ((1 << SH_U) - 1)) << 32) | rec;
        }
    }
    __syncthreads();
    {
        int w = tid >> 6, lane = tid & 63;
        for (int b = w; b < 256; b += 8) {
            int c = cnt[b];
            if (!c) continue;
            int cp = (c + PAD - 1) & ~(PAD - 1);
            int lb = loffs[b];
            long gb = gbase[b];
            for (int r = lane; r < cp; r += 64)
                stg_u[gb + r] = (r < c) ? stage[lb + r] : DUMMY64;
        }
    }
}

// exclusive scan of per-bucket REAL counts -> CSR bucket bases; write sentinel
__global__ __launch_bounds__(512)
void bucket_scan_kernel(const int* __restrict__ rc, int nb, int E,
                        int* __restrict__ bbase, int* __restrict__ rowp_sentinel) {
    __shared__ int wsum[8];
    int tid = threadIdx.x;
    int v = (tid < nb) ? rc[tid] : 0;
    int excl = excl_scan_512t(v, wsum);
    if (tid < nb) bbase[tid] = excl;
    if (tid == 0) *rowp_sentinel = E;
}

// Per bucket: histogram -> scan -> rowptr; scatter records into LDS sorted by
// row; burst-copy the sorted run to CSR (coalesced, write amp ~1).
__global__ __launch_bounds__(1024)
void passB_kernel(int nb_i, int cap_i, int N_i,
                  int nb_u, int cap_u, int N_u,
                  const int* __restrict__ cur_i, const int* __restrict__ cur_u,
                  const int* __restrict__ rc_i, const int* __restrict__ rc_u,
                  const int* __restrict__ bb_i, const int* __restrict__ bb_u,
                  const u64* __restrict__ stg_i, const u64* __restrict__ stg_u,
                  int* __restrict__ rowp_i, int* __restrict__ rowp_u,
                  u32* __restrict__ csr_i, u32* __restrict__ csr_u) {
    __shared__ u32 srt[SRT_CAP];
    __shared__ int lcnt[512];
    __shared__ int wsum[16];
    int b = blockIdx.x;
    int dir_item = (b < nb_i);
    int bb = dir_item ? b : b - nb_i;
    int SH = dir_item ? SH_I : SH_U;
    int cap = dir_item ? cap_i : cap_u;
    int N = dir_item ? N_i : N_u;
    const u64* stg = dir_item ? stg_i : stg_u;
    int ebase = dir_item ? bb_i[bb] : bb_u[bb];
    int scount = (dir_item ? cur_i[bb] : cur_u[bb]) - bb * cap;   // incl. dummies
    int realcnt = dir_item ? rc_i[bb] : rc_u[bb];
    int* rowp = dir_item ? rowp_i : rowp_u;
    u32* csr = dir_item ? csr_i : csr_u;

    int rows0 = bb << SH;
    int nrows = min(1 << SH, N - rows0);
    int tid = threadIdx.x;
    const uint4* stg4 = (const uint4*)(stg + (size_t)bb * cap);
    int npair = scount >> 1;                 // scount is a multiple of PAD=8

    if (tid < 512) lcnt[tid] = 0;
    __syncthreads();
    for (int k = tid; k < npair; k += 1024) {
        uint4 w = stg4[k];
        if ((int)w.y >= 0) atomicAdd(&lcnt[(int)w.y], 1);
        if ((int)w.w >= 0) atomicAdd(&lcnt[(int)w.w], 1);
    }
    __syncthreads();
    int v = (tid < 512) ? lcnt[tid] : 0;
    int excl = excl_scan_1024t(v, wsum);
    if (tid < 512) lcnt[tid] = excl;         // becomes bucket-local running cursor
    if (tid < nrows) rowp[rows0 + tid] = ebase + excl;
    __syncthreads();
    // scatter into LDS sorted by row (guard vs statistically-impossible overflow)
    for (int k = tid; k < npair; k += 1024) {
        uint4 w = stg4[k];
        if ((int)w.y >= 0) {
            int p = atomicAdd(&lcnt[(int)w.y], 1);
            if (p < SRT_CAP) srt[p] = w.x;
        }
        if ((int)w.w >= 0) {
            int p = atomicAdd(&lcnt[(int)w.w], 1);
            if (p < SRT_CAP) srt[p] = w.z;
        }
    }
    __syncthreads();
    // coalesced burst copy to global CSR
    int n = min(realcnt, SRT_CAP);
    for (int k = tid; k < n; k += 1024)
        csr[ebase + k] = srt[k];
}

// ---------------- propagation ----------------

// Wave-per-row SpMM over a packed-bf16 source table, 16 edges in flight.
// lane = (g:2 | el:4). 4B records: src = rec & 0x1ffff,
// val_f32_bits = (rec & 0xfffe0000) >> 1  (bf16<<16 with sign 0).
// SAMPLED: row = idx[slot], output keyed by slot (for last layer).
template<int SAMPLED>
__global__ __launch_bounds__(256)
void spmm_kernel(const int* __restrict__ rowptr, const u32* __restrict__ csr,
                 const u32* __restrict__ src16, u32* __restrict__ dst16,
                 const int* __restrict__ idx, int nrows) {
    int slot = blockIdx.x * 4 + (threadIdx.x >> 6);
    if (slot >= nrows) return;
    int row = SAMPLED ? idx[slot] : slot;
    int lane = threadIdx.x & 63;
    int g = lane >> 4;
    int el = lane & 15;
    int beg = rowptr[row], end = rowptr[row + 1];
    const uint2* SB = (const uint2*)src16 + el;   // row stride = 16 uint2 (128B)
    float4 A0 = {0,0,0,0}, A1 = {0,0,0,0}, A2 = {0,0,0,0}, A3 = {0,0,0,0};
    for (int k = beg + g; k < end; k += 16) {
        u32 r0 = csr[k];
        u32 r1 = csr[k + 4];
        u32 r2 = csr[k + 8];
        u32 r3 = csr[k + 12];
        bool m1 = (k + 4) < end, m2 = (k + 8) < end, m3 = (k + 12) < end;
        int s0 = (int)(r0 & 0x1ffffu);
        int s1 = m1 ? (int)(r1 & 0x1ffffu) : 0;
        int s2 = m2 ? (int)(r2 & 0x1ffffu) : 0;
        int s3 = m3 ? (int)(r3 & 0x1ffffu) : 0;
        float v0 = __uint_as_float((r0 & 0xfffe0000u) >> 1);
        float v1 = m1 ? __uint_as_float((r1 & 0xfffe0000u) >> 1) : 0.f;
        float v2 = m2 ? __uint_as_float((r2 & 0xfffe0000u) >> 1) : 0.f;
        float v3 = m3 ? __uint_as_float((r3 & 0xfffe0000u) >> 1) : 0.f;
        uint2 w0 = SB[(size_t)s0 * 16];
        uint2 w1 = SB[(size_t)s1 * 16];
        uint2 w2 = SB[(size_t)s2 * 16];
        uint2 w3 = SB[(size_t)s3 * 16];
        A0.x += v0 * __uint_as_float(w0.x << 16);
        A0.y += v0 * __uint_as_float(w0.x & 0xffff0000u);
        A0.z += v0 * __uint_as_float(w0.y << 16);
        A0.w += v0 * __uint_as_float(w0.y & 0xffff0000u);
        A1.x += v1 * __uint_as_float(w1.x << 16);
        A1.y += v1 * __uint_as_float(w1.x & 0xffff0000u);
        A1.z += v1 * __uint_as_float(w1.y << 16);
        A1.w += v1 * __uint_as_float(w1.y & 0xffff0000u);
        A2.x += v2 * __uint_as_float(w2.x << 16);
        A2.y += v2 * __uint_as_float(w2.x & 0xffff0000u);
        A2.z += v2 * __uint_as_float(w2.y << 16);
        A2.w += v2 * __uint_as_float(w2.y & 0xffff0000u);
        A3.x += v3 * __uint_as_float(w3.x << 16);
        A3.y += v3 * __uint_as_float(w3.x & 0xffff0000u);
        A3.z += v3 * __uint_as_float(w3.y << 16);
        A3.w += v3 * __uint_as_float(w3.y & 0xffff0000u);
    }
    float4 a;
    a.x = (A0.x + A1.x) + (A2.x + A3.x);
    a.y = (A0.y + A1.y) + (A2.y + A3.y);
    a.z = (A0.z + A1.z) + (A2.z + A3.z);
    a.w = (A0.w + A1.w) + (A2.w + A3.w);
    a.x += __shfl_xor(a.x, 16, 64); a.x += __shfl_xor(a.x, 32, 64);
    a.y += __shfl_xor(a.y, 16, 64); a.y += __shfl_xor(a.y, 32, 64);
    a.z += __shfl_xor(a.z, 16, 64); a.z += __shfl_xor(a.z, 32, 64);
    a.w += __shfl_xor(a.w, 16, 64); a.w += __shfl_xor(a.w, 32, 64);
    if (g == 0) {
        ((uint2*)dst16)[(size_t)slot * 16 + el] =
            make_uint2(pack2_bf16(a.x, a.y), pack2_bf16(a.z, a.w));
    }
}

// Final score: per sampled pair, sum orig f32 + e1,e2 (by id) + e3 (by slot),
// dot, scale. 16 lanes per pair.
__global__ __launch_bounds__(256)
void score_kernel(const float* __restrict__ user_emb, const float* __restrict__ item_emb,
                  const u32* __restrict__ eu1, const u32* __restrict__ eu2,
                  const u32* __restrict__ eu3s,
                  const u32* __restrict__ ei1, const u32* __restrict__ ei2,
                  const u32* __restrict__ ei3s,
                  const int* __restrict__ users, const int* __restrict__ items,
                  float* __restrict__ out, int B, float inv2) {
    int gid = blockIdx.x * blockDim.x + threadIdx.x;
    int b = gid >> 4;
    int lane = gid & 15;
    if (b >= B) return;
    int u = users[b], it = items[b];

    float4 su = ((const float4*)(user_emb + (size_t)u * D))[lane];
    uint2 p1 = ((const uint2*)eu1)[(size_t)u * 16 + lane];
    uint2 p2 = ((const uint2*)eu2)[(size_t)u * 16 + lane];
    uint2 p3 = ((const uint2*)eu3s)[(size_t)b * 16 + lane];
    su.x += __uint_as_float(p1.x << 16) + __uint_as_float(p2.x << 16) + __uint_as_float(p3.x << 16);
    su.y += __uint_as_float(p1.x & 0xffff0000u) + __uint_as_float(p2.x & 0xffff0000u) + __uint_as_float(p3.x & 0xffff0000u);
    su.z += __uint_as_float(p1.y << 16) + __uint_as_float(p2.y << 16) + __uint_as_float(p3.y << 16);
    su.w += __uint_as_float(p1.y & 0xffff0000u) + __uint_as_float(p2.y & 0xffff0000u) + __uint_as_float(p3.y & 0xffff0000u);

    float4 si = ((const float4*)(item_emb + (size_t)it * D))[lane];
    uint2 q1 = ((const uint2*)ei1)[(size_t)it * 16 + lane];
    uint2 q2 = ((const uint2*)ei2)[(size_t)it * 16 + lane];
    uint2 q3 = ((const uint2*)ei3s)[(size_t)b * 16 + lane];
    si.x += __uint_as_float(q1.x << 16) + __uint_as_float(q2.x << 16) + __uint_as_float(q3.x << 16);
    si.y += __uint_as_float(q1.x & 0xffff0000u) + __uint_as_float(q2.x & 0xffff0000u) + __uint_as_float(q3.x & 0xffff0000u);
    si.z += __uint_as_float(q1.y << 16) + __uint_as_float(q2.y << 16) + __uint_as_float(q3.y << 16);
    si.w += __uint_as_float(q1.y & 0xffff0000u) + __uint_as_float(q2.y & 0xffff0000u) + __uint_as_float(q3.y & 0xffff0000u);

    float d = su.x * si.x + su.y * si.y + su.z * si.z + su.w * si.w;
    #pragma unroll
    for (int m = 1; m < 16; m <<= 1) d += __shfl_xor(d, m, 64);
    if (lane == 0) out[b] = d * inv2;
}

// ---------------- launch ----------------

extern "C" void kernel_launch(void* const* d_in, const int* in_sizes, int n_in,
                              void* d_out, int out_size, void* d_ws, size_t ws_size,
                              hipStream_t stream) {
    const float* user_emb = (const float*)d_in[0];
    const float* item_emb = (const float*)d_in[1];
    const float* edge_vals = (const float*)d_in[2];
    const int* edge_u = (const int*)d_in[3];
    const int* edge_i = (const int*)d_in[4];
    const int* users = (const int*)d_in[5];
    const int* items = (const int*)d_in[6];
    float* out = (float*)d_out;

    const int U = in_sizes[0] / D;
    const int I = in_sizes[1] / D;
    const int E = in_sizes[2];
    const int B = in_sizes[5];

    const int nb_i = (I + (1 << SH_I) - 1) >> SH_I;
    const int nb_u = (U + (1 << SH_U) - 1) >> SH_U;
    const int tiles = (E + TILE - 1) / TILE;
    // cap: mean real + worst-case pad (PAD-1 per block) + variance slack
    const int cap_i = ((E / nb_i + tiles * (PAD - 1) + 1024 + 63) / 64) * 64;
    const int cap_u = ((E / nb_u + tiles * (PAD - 1) + 1024 + 63) / 64) * 64;

    // carve workspace (256B aligned)
    char* p = (char*)d_ws;
    size_t off = 0;
    auto alloc = [&](size_t bytes) -> char* {
        char* r = p + off;
        off = (off + bytes + 255) & ~(size_t)255;
        return r;
    };
    u32* ub16  = (u32*)alloc((size_t)U * (D / 2) * 4);  // packed bf16 originals
    u32* ib16  = (u32*)alloc((size_t)I * (D / 2) * 4);
    u32* eu1   = (u32*)alloc((size_t)U * (D / 2) * 4);  // dense layer-1/2 tables
    u32* eu2   = (u32*)alloc((size_t)U * (D / 2) * 4);
    u32* ei1   = (u32*)alloc((size_t)I * (D / 2) * 4);
    u32* ei2   = (u32*)alloc((size_t)I * (D / 2) * 4);
    u32* eu3s  = (u32*)alloc((size_t)B * (D / 2) * 4);  // sampled layer-3 (by slot)
    u32* ei3s  = (u32*)alloc((size_t)B * (D / 2) * 4);
    u32* csr_u = (u32*)alloc((size_t)(E + 16) * 4);
    u32* csr_i = (u32*)alloc((size_t)(E + 16) * 4);
    int* rowp_u = (int*)alloc((size_t)(U + 1) * 4);
    int* rowp_i = (int*)alloc((size_t)(I + 1) * 4);
    int* cur_i  = (int*)alloc((size_t)nb_i * 4);
    int* cur_u  = (int*)alloc((size_t)nb_u * 4);
    int* rc_i   = (int*)alloc((size_t)nb_i * 4);
    int* rc_u   = (int*)alloc((size_t)nb_u * 4);
    int* bb_i   = (int*)alloc((size_t)nb_i * 4);
    int* bb_u   = (int*)alloc((size_t)nb_u * 4);
    u64* stg_i  = (u64*)alloc((size_t)nb_i * cap_i * 8);
    u64* stg_u  = (u64*)alloc((size_t)nb_u * cap_u * 8);
    if (off > ws_size) return;    // workspace too small -> fail loudly

    // 0. convert original embeddings to packed bf16 gather tables
    cvt_bf16_kernel<<<1024, 256, 0, stream>>>((const float2*)user_emb, ub16, (long)U * (D / 2));
    cvt_bf16_kernel<<<1024, 256, 0, stream>>>((const float2*)item_emb, ib16, (long)I * (D / 2));

    // 1. CSR build (both directions)
    init_cursors_kernel<<<1, 512, 0, stream>>>(cur_i, rc_i, nb_i, cap_i,
                                               cur_u, rc_u, nb_u, cap_u);
    passA_kernel<<<tiles, 512, 0, stream>>>(edge_u, edge_i, edge_vals, E,
                                            cur_i, rc_i, cur_u, rc_u,
                                            stg_i, stg_u);
    bucket_scan_kernel<<<1, 512, 0, stream>>>(rc_i, nb_i, E, bb_i, rowp_i + I);
    bucket_scan_kernel<<<1, 512, 0, stream>>>(rc_u, nb_u, E, bb_u, rowp_u + U);
    passB_kernel<<<nb_i + nb_u, 1024, 0, stream>>>(nb_i, cap_i, I, nb_u, cap_u, U,
                                                   cur_i, cur_u, rc_i, rc_u,
                                                   bb_i, bb_u,
                                                   stg_i, stg_u, rowp_i, rowp_u,
                                                   csr_i, csr_u);

    // 2. propagation: layers 1-2 dense, layer 3 only for sampled rows
    int blk_i = (I + 3) / 4;
    int blk_u = (U + 3) / 4;
    int blk_s = (B + 3) / 4;
    spmm_kernel<0><<<blk_i, 256, 0, stream>>>(rowp_i, csr_i, ub16, ei1, nullptr, I);
    spmm_kernel<0><<<blk_u, 256, 0, stream>>>(rowp_u, csr_u, ib16, eu1, nullptr, U);
    spmm_kernel<0><<<blk_i, 256, 0, stream>>>(rowp_i, csr_i, eu1, ei2, nullptr, I);
    spmm_kernel<0><<<blk_u, 256, 0, stream>>>(rowp_u, csr_u, ei1, eu2, nullptr, U);
    spmm_kernel<1><<<blk_s, 256, 0, stream>>>(rowp_i, csr_i, eu2, ei3s, items, B);
    spmm_kernel<1><<<blk_s, 256, 0, stream>>>(rowp_u, csr_u, ei2, eu3s, users, B);

    // 3. final scores for sampled pairs: sum four layers, dot, scale by 1/16
    int blk_sc = (B * 16 + 255) / 256;
    score_kernel<<<blk_sc, 256, 0, stream>>>(user_emb, item_emb,
                                             eu1, eu2, eu3s, ei1, ei2, ei3s,
                                             users, items, out, B, 0.0625f);
}